// Round 21
// baseline (4646.983 us; speedup 1.0000x reference)
//
#include <hip/hip_runtime.h>
#include <hip/hip_bf16.h>
#include <cstdint>
#include <cstddef>

#define L_SEQ 2048
#define BATCH 4
#define DM    512
#define DI    3072
#define NROWS (BATCH * L_SEQ)   // 8192
#define PROJW 1544              // 3*512 + 8
#define CTILE 16
#define BDI   (BATCH * DI)      // 12288
#define SB    64                // ttt staging superblock (tokens)
#define NSB   (L_SEQ / SB)      // 32
#define CHT   16                // ttt serial sub-chunk
#define LCH   128               // longhorn chunk tokens
#define NLCH  (L_SEQ / LCH)     // 16

using bf16 = __hip_bfloat16;

typedef __attribute__((ext_vector_type(8))) short short8v;
typedef __attribute__((ext_vector_type(4))) float f32x4;

// ---------------------------------------------------------------- utilities

__device__ __forceinline__ float sigmoidf_(float x) { return 1.f / (1.f + __expf(-x)); }
__device__ __forceinline__ float us2f(unsigned int u) {
    union { unsigned int i; float f; } c; c.i = u << 16; return c.f;
}
__device__ __forceinline__ bf16  f2b(float f) { return __float2bfloat16(f); }
__device__ __forceinline__ float b2f(bf16 v)  { return __bfloat162float(v); }
__device__ __forceinline__ void st1(float* p, float v) { *p = v; }
__device__ __forceinline__ void st1(bf16* p, float v)  { *p = f2b(v); }

// DPP-based wave64 sum -> uniform value (validated R4-R20)
template <int CTRL>
__device__ __forceinline__ float dppadd_(float x) {
    int s = __builtin_amdgcn_update_dpp(0, __builtin_bit_cast(int, x), CTRL, 0xF, 0xF, true);
    return x + __builtin_bit_cast(float, s);
}
__device__ __forceinline__ float wave_sum_u(float x) {
    x = dppadd_<0x111>(x);
    x = dppadd_<0x112>(x);
    x = dppadd_<0x114>(x);
    x = dppadd_<0x118>(x);
    x = dppadd_<0x142>(x);
    x = dppadd_<0x143>(x);
    return __builtin_bit_cast(float,
        __builtin_amdgcn_readlane(__builtin_bit_cast(int, x), 63));
}

// ---------------------------------------------------------------- residual copy (ws-too-small fallback only)
__global__ __launch_bounds__(256) void copy4_k(const float4* __restrict__ in,
                                               float4* __restrict__ out, int n) {
    int i = blockIdx.x * 256 + threadIdx.x;
    if (i < n) out[i] = in[i];
}

// ---------------------------------------------------------------- f32 -> bf16 weight convert
__global__ __launch_bounds__(256) void cvt_k(const float* __restrict__ in,
                                             bf16* __restrict__ out, int n4) {
    int i = blockIdx.x * 256 + threadIdx.x;
    if (i >= n4) return;
    float4 v = ((const float4*)in)[i];
    out[4 * i + 0] = f2b(v.x);
    out[4 * i + 1] = f2b(v.y);
    out[4 * i + 2] = f2b(v.z);
    out[4 * i + 3] = f2b(v.w);
}

// concat 3x [512][512] f32 -> bf16 wcat[1536][512]
__global__ __launch_bounds__(256) void cvt3_k(const float* __restrict__ a,
                                              const float* __restrict__ b,
                                              const float* __restrict__ c,
                                              bf16* __restrict__ out) {
    int i = blockIdx.x * 256 + threadIdx.x;
    const int seg = 512 * 512 / 4;
    if (i >= 3 * seg) return;
    const float* src = (i < seg) ? a : (i < 2 * seg) ? b : c;
    int j = (i < seg) ? i : (i < 2 * seg) ? i - seg : i - 2 * seg;
    float4 v = ((const float4*)src)[j];
    bf16* o = out + (size_t)i * 4;
    o[0] = f2b(v.x); o[1] = f2b(v.y); o[2] = f2b(v.z); o[3] = f2b(v.w);
}

// merged cvt: reduce | qkv | wo  (run after longhorn, over dead lpq region)
#define C_RED  393216                  // reduce f4 units
#define C_QKV  197632                  // qkv
#define C_WO   65536                   // wo
__global__ __launch_bounds__(256) void cvt_rqw_k(const float* __restrict__ reduce_w,
                                                 const float* __restrict__ qkv_w,
                                                 const float* __restrict__ wo_w,
                                                 bf16* __restrict__ redb,
                                                 bf16* __restrict__ qkvb,
                                                 bf16* __restrict__ wob) {
    int i = blockIdx.x * 256 + threadIdx.x;
    const float* src;
    bf16* dst;
    int j;
    if (i < C_RED)                     { src = reduce_w; dst = redb; j = i; }
    else if (i < C_RED + C_QKV)        { src = qkv_w;    dst = qkvb; j = i - C_RED; }
    else if (i < C_RED + C_QKV + C_WO) { src = wo_w;     dst = wob;  j = i - C_RED - C_QKV; }
    else return;
    float4 v = ((const float4*)src)[j];
    bf16* o = dst + (size_t)j * 4;
    o[0] = f2b(v.x); o[1] = f2b(v.y); o[2] = f2b(v.z); o[3] = f2b(v.w);
}

// ---------------------------------------------------------------- rmsnorm + residual copy fused
__global__ __launch_bounds__(256) void rmsnorm_res_k(const float* __restrict__ x,
                                                     const float* __restrict__ w,
                                                     bf16* __restrict__ xn,
                                                     float* __restrict__ res) {
    int r = blockIdx.x, tid = threadIdx.x;
    const float* row = x + (size_t)r * DM;
    float v0 = row[tid], v1 = row[tid + 256];
    float q = v0 * v0 + v1 * v1;
#pragma unroll
    for (int off = 32; off; off >>= 1) q += __shfl_xor(q, off);
    __shared__ float sm[4];
    if ((tid & 63) == 0) sm[tid >> 6] = q;
    __syncthreads();
    q = sm[0] + sm[1] + sm[2] + sm[3];
    float scale = rsqrtf(q * (1.f / 512.f) + 1e-5f);
    bf16* orow = xn + (size_t)r * DM;
    float* rrow = res + (size_t)r * DM;
    orow[tid]       = f2b(v0 * scale * w[tid]);
    orow[tid + 256] = f2b(v1 * scale * w[tid + 256]);
    rrow[tid]       = v0;
    rrow[tid + 256] = v1;
}

// ---------------------------------------------------------------- bf16 MFMA GEMM (validated R3)
template <int BIAS, typename TC>
__global__ __launch_bounds__(256) void gemm_mfma(const bf16* __restrict__ A, int lda,
                                                 const bf16* __restrict__ Wb, int ldw,
                                                 const float* __restrict__ bias,
                                                 TC* __restrict__ C, int ldc,
                                                 int N, int K) {
    __shared__ __align__(16) bf16 As[128 * 48];
    __shared__ __align__(16) bf16 Ws[128 * 48];
    const int tid = threadIdx.x;
    const int lane = tid & 63;
    const int widx = tid >> 6;
    const int bm = blockIdx.x * 128;
    const int bn = blockIdx.y * 128;
    const int wr = (widx >> 1) * 64;
    const int wc = (widx & 1) * 64;

    f32x4 acc[4][4];
#pragma unroll
    for (int i = 0; i < 4; ++i)
#pragma unroll
        for (int j = 0; j < 4; ++j) acc[i][j] = (f32x4){0.f, 0.f, 0.f, 0.f};

    const int r0 = tid >> 2;
    const int c0 = tid & 3;
    const int frow = lane & 15;
    const int fk = (lane >> 4) * 8;

    int n0 = bn + r0;       if (n0 > N - 1) n0 = N - 1;
    int n1 = bn + r0 + 64;  if (n1 > N - 1) n1 = N - 1;
    const bf16* pa0 = A + (size_t)(bm + r0) * lda + c0 * 8;
    const bf16* pa1 = A + (size_t)(bm + r0 + 64) * lda + c0 * 8;
    const bf16* pb0 = Wb + (size_t)n0 * ldw + c0 * 8;
    const bf16* pb1 = Wb + (size_t)n1 * ldw + c0 * 8;

    for (int k0 = 0; k0 < K; k0 += 32) {
        short8v a0 = *(const short8v*)(pa0 + k0);
        short8v a1 = *(const short8v*)(pa1 + k0);
        short8v b0 = *(const short8v*)(pb0 + k0);
        short8v b1 = *(const short8v*)(pb1 + k0);
        __syncthreads();
        *(short8v*)&As[r0 * 48 + c0 * 8] = a0;
        *(short8v*)&As[(r0 + 64) * 48 + c0 * 8] = a1;
        *(short8v*)&Ws[r0 * 48 + c0 * 8] = b0;
        *(short8v*)&Ws[(r0 + 64) * 48 + c0 * 8] = b1;
        __syncthreads();
        short8v af[4], bg[4];
#pragma unroll
        for (int mi = 0; mi < 4; ++mi)
            af[mi] = *(const short8v*)&As[(wr + mi * 16 + frow) * 48 + fk];
#pragma unroll
        for (int ni = 0; ni < 4; ++ni)
            bg[ni] = *(const short8v*)&Ws[(wc + ni * 16 + frow) * 48 + fk];
#pragma unroll
        for (int mi = 0; mi < 4; ++mi)
#pragma unroll
            for (int ni = 0; ni < 4; ++ni)
                acc[mi][ni] = __builtin_amdgcn_mfma_f32_16x16x32_bf16(
                    af[mi], bg[ni], acc[mi][ni], 0, 0, 0);
    }

#pragma unroll
    for (int ni = 0; ni < 4; ++ni) {
        int col = bn + wc + ni * 16 + (lane & 15);
        if (col < N) {
            float bz = BIAS ? bias[col] : 0.f;
#pragma unroll
            for (int mi = 0; mi < 4; ++mi) {
                int rbase = bm + wr + mi * 16 + (lane >> 4) * 4;
#pragma unroll
                for (int r = 0; r < 4; ++r) {
                    float v = acc[mi][ni][r] + bz;
                    st1(&C[(size_t)(rbase + r) * ldc + col], v);
                }
            }
        }
    }
}

// ---------------------------------------------------------------- merged in_proj GEMM: N=6144, split C (bufX | bufZ)
__global__ __launch_bounds__(256) void gemm_inproj(const bf16* __restrict__ A,
                                                   const bf16* __restrict__ Wb,
                                                   bf16* __restrict__ cx,
                                                   bf16* __restrict__ cz) {
    __shared__ __align__(16) bf16 As[128 * 48];
    __shared__ __align__(16) bf16 Ws[128 * 48];
    const int tid = threadIdx.x;
    const int lane = tid & 63;
    const int widx = tid >> 6;
    const int bm = blockIdx.x * 128;
    const int bn = blockIdx.y * 128;
    const int wr = (widx >> 1) * 64;
    const int wc = (widx & 1) * 64;

    f32x4 acc[4][4];
#pragma unroll
    for (int i = 0; i < 4; ++i)
#pragma unroll
        for (int j = 0; j < 4; ++j) acc[i][j] = (f32x4){0.f, 0.f, 0.f, 0.f};

    const int r0 = tid >> 2;
    const int c0 = tid & 3;
    const int frow = lane & 15;
    const int fk = (lane >> 4) * 8;

    const bf16* pa0 = A + (size_t)(bm + r0) * DM + c0 * 8;
    const bf16* pa1 = A + (size_t)(bm + r0 + 64) * DM + c0 * 8;
    const bf16* pb0 = Wb + (size_t)(bn + r0) * DM + c0 * 8;
    const bf16* pb1 = Wb + (size_t)(bn + r0 + 64) * DM + c0 * 8;

    for (int k0 = 0; k0 < DM; k0 += 32) {
        short8v a0 = *(const short8v*)(pa0 + k0);
        short8v a1 = *(const short8v*)(pa1 + k0);
        short8v b0 = *(const short8v*)(pb0 + k0);
        short8v b1 = *(const short8v*)(pb1 + k0);
        __syncthreads();
        *(short8v*)&As[r0 * 48 + c0 * 8] = a0;
        *(short8v*)&As[(r0 + 64) * 48 + c0 * 8] = a1;
        *(short8v*)&Ws[r0 * 48 + c0 * 8] = b0;
        *(short8v*)&Ws[(r0 + 64) * 48 + c0 * 8] = b1;
        __syncthreads();
        short8v af[4], bg[4];
#pragma unroll
        for (int mi = 0; mi < 4; ++mi)
            af[mi] = *(const short8v*)&As[(wr + mi * 16 + frow) * 48 + fk];
#pragma unroll
        for (int ni = 0; ni < 4; ++ni)
            bg[ni] = *(const short8v*)&Ws[(wc + ni * 16 + frow) * 48 + fk];
#pragma unroll
        for (int mi = 0; mi < 4; ++mi)
#pragma unroll
            for (int ni = 0; ni < 4; ++ni)
                acc[mi][ni] = __builtin_amdgcn_mfma_f32_16x16x32_bf16(
                    af[mi], bg[ni], acc[mi][ni], 0, 0, 0);
    }

    bf16* Cb = (bn < DI) ? cx : cz;
    const int coff = (bn < DI) ? 0 : DI;
#pragma unroll
    for (int ni = 0; ni < 4; ++ni) {
        int col = bn + wc + ni * 16 + (lane & 15) - coff;
#pragma unroll
        for (int mi = 0; mi < 4; ++mi) {
            int rbase = bm + wr + mi * 16 + (lane >> 4) * 4;
#pragma unroll
            for (int r = 0; r < 4; ++r)
                Cb[(size_t)(rbase + r) * DI + col] = f2b(acc[mi][ni][r]);
        }
    }
}

// ---------------------------------------------------------------- conv: boundary row copy
__global__ __launch_bounds__(256) void conv_boundary_k(const bf16* __restrict__ x,
                                                       bf16* __restrict__ side) {
    int idx = blockIdx.x * 256 + threadIdx.x;
    const int total = (L_SEQ / CTILE - 1) * 2 * BDI;
    if (idx >= total) return;
    int col = idx % BDI;
    int rr = idx / BDI;
    int tile = (rr >> 1) + 1;
    int r = rr & 1;
    int b = col / DI, d = col % DI;
    int l = tile * CTILE - 2 + r;
    side[idx] = x[((size_t)b * L_SEQ + l) * DI + d];
}

// ---------------------------------------------------------------- conv tile: causal depthwise conv3 + silu
__global__ __launch_bounds__(256) void conv_tile_k(bf16* __restrict__ x,
                                                   const bf16* __restrict__ side,
                                                   const float* __restrict__ cw,
                                                   const float* __restrict__ cb) {
    int idx = blockIdx.x * 256 + threadIdx.x;
    const int total = (L_SEQ / CTILE) * BDI;
    if (idx >= total) return;
    int col = idx % BDI;
    int tile = idx / BDI;
    int b = col / DI, d = col % DI;
    float w0 = cw[3 * d], w1 = cw[3 * d + 1], w2 = cw[3 * d + 2], bias = cb[d];
    size_t base = ((size_t)b * L_SEQ + tile * CTILE) * DI + d;
    float xm2, xm1;
    if (tile == 0) { xm2 = 0.f; xm1 = 0.f; }
    else {
        const bf16* sp = side + ((size_t)(tile - 1) * 2) * BDI + col;
        xm2 = b2f(sp[0]);
        xm1 = b2f(sp[BDI]);
    }
    float cur = b2f(x[base]);
#pragma unroll
    for (int i = 0; i < CTILE; ++i) {
        float nxt = (i + 1 < CTILE) ? b2f(x[base + (size_t)(i + 1) * DI]) : 0.f;
        float a = bias + w0 * xm2 + w1 * xm1 + w2 * cur;
        x[base + (size_t)i * DI] = f2b(a * sigmoidf_(a));
        xm2 = xm1; xm1 = cur; cur = nxt;
    }
}

// ---------------------------------------------------------------- longhorn chunked scan (validated R13; LCH=128)
__global__ __launch_bounds__(256) void longhorn_p1(const bf16* __restrict__ xb,
                                                   const float* __restrict__ xdbl,
                                                   const float* __restrict__ dtw,
                                                   const float* __restrict__ dtb_v,
                                                   float* __restrict__ pq) {
    int idx = blockIdx.x * 256 + threadIdx.x;
    int ch = idx / BDI;
    int col = idx % BDI;
    int b = col / DI, d = col % DI;
    float w32[32];
#pragma unroll
    for (int i = 0; i < 32; ++i) w32[i] = dtw[d * 32 + i];
    float dtb = dtb_v[d];
    float P[8] = {1.f, 1.f, 1.f, 1.f, 1.f, 1.f, 1.f, 1.f};
    float Q[8] = {0.f, 0.f, 0.f, 0.f, 0.f, 0.f, 0.f, 0.f};
    size_t rbase = ((size_t)b * L_SEQ + ch * LCH) * DI + d;
    const float* xdb = xdbl + ((size_t)b * L_SEQ + ch * LCH) * 48;

    float xv = b2f(xb[rbase]);
    for (int t = 0; t < LCH; ++t) {
        float x_c = xv;
        if (t + 1 < LCH) xv = b2f(xb[rbase + (size_t)(t + 1) * DI]);
        const float* row = xdb + (size_t)t * 48;
        float dt_c = 0.f;
#pragma unroll
        for (int i = 0; i < 32; i += 4) {
            float4 r4 = *(const float4*)(row + i);
            dt_c = fmaf(r4.x, w32[i + 0], dt_c);
            dt_c = fmaf(r4.y, w32[i + 1], dt_c);
            dt_c = fmaf(r4.z, w32[i + 2], dt_c);
            dt_c = fmaf(r4.w, w32[i + 3], dt_c);
        }
        float kq[8];
#pragma unroll
        for (int i = 0; i < 8; i += 4) *(float4*)&kq[i] = *(const float4*)(row + 32 + i);
        float sig = sigmoidf_(dt_c + dtb);
        float ksq = 0.f;
#pragma unroll
        for (int n = 0; n < 8; ++n) ksq = fmaf(kq[n], kq[n], ksq);
        float dts = sig / (1.f + sig * ksq);
#pragma unroll
        for (int n = 0; n < 8; ++n) {
            float dB = dts * kq[n];
            float a = 1.f - dB * kq[n];
            P[n] *= a;
            Q[n] = fmaf(Q[n], a, x_c * dB);
        }
    }
    float* o = pq + (size_t)idx * 16;
#pragma unroll
    for (int n = 0; n < 8; n += 4) {
        *(float4*)(o + n)     = make_float4(P[n], P[n + 1], P[n + 2], P[n + 3]);
        *(float4*)(o + 8 + n) = make_float4(Q[n], Q[n + 1], Q[n + 2], Q[n + 3]);
    }
}

__global__ __launch_bounds__(256) void longhorn_p2(float* __restrict__ pq) {
    int col = blockIdx.x * 256 + threadIdx.x;
    float s[8] = {0.f, 0.f, 0.f, 0.f, 0.f, 0.f, 0.f, 0.f};
    for (int c = 0; c < NLCH; ++c) {
        float* base = pq + ((size_t)c * BDI + col) * 16;
        float P[8], Q[8];
#pragma unroll
        for (int n = 0; n < 8; n += 4) {
            *(float4*)&P[n] = *(const float4*)(base + n);
            *(float4*)&Q[n] = *(const float4*)(base + 8 + n);
        }
#pragma unroll
        for (int n = 0; n < 8; n += 4)
            *(float4*)(base + n) = make_float4(s[n], s[n + 1], s[n + 2], s[n + 3]);
#pragma unroll
        for (int n = 0; n < 8; ++n) s[n] = fmaf(P[n], s[n], Q[n]);
    }
}

__global__ __launch_bounds__(256) void longhorn_p3(bf16* __restrict__ xb_y,
                                                   const bf16* __restrict__ z,
                                                   const float* __restrict__ xdbl,
                                                   const float* __restrict__ dtw,
                                                   const float* __restrict__ dtb_v,
                                                   const float* __restrict__ Dv,
                                                   const float* __restrict__ pq) {
    int idx = blockIdx.x * 256 + threadIdx.x;
    int ch = idx / BDI;
    int col = idx % BDI;
    int b = col / DI, d = col % DI;
    float w32[32];
#pragma unroll
    for (int i = 0; i < 32; ++i) w32[i] = dtw[d * 32 + i];
    float dtb = dtb_v[d], Dd = Dv[d];
    float s[8];
    {
        const float* base = pq + (size_t)idx * 16;
#pragma unroll
        for (int n = 0; n < 8; n += 4) *(float4*)&s[n] = *(const float4*)(base + n);
    }
    size_t rbase = ((size_t)b * L_SEQ + ch * LCH) * DI + d;
    const float* xdb = xdbl + ((size_t)b * L_SEQ + ch * LCH) * 48;

    float xv = b2f(xb_y[rbase]);
    float zv = b2f(z[rbase]);
    for (int t = 0; t < LCH; ++t) {
        float x_c = xv, z_c = zv;
        if (t + 1 < LCH) {
            size_t nidx = rbase + (size_t)(t + 1) * DI;
            xv = b2f(xb_y[nidx]);
            zv = b2f(z[nidx]);
        }
        const float* row = xdb + (size_t)t * 48;
        float dt_c = 0.f;
#pragma unroll
        for (int i = 0; i < 32; i += 4) {
            float4 r4 = *(const float4*)(row + i);
            dt_c = fmaf(r4.x, w32[i + 0], dt_c);
            dt_c = fmaf(r4.y, w32[i + 1], dt_c);
            dt_c = fmaf(r4.z, w32[i + 2], dt_c);
            dt_c = fmaf(r4.w, w32[i + 3], dt_c);
        }
        float kq[16];
#pragma unroll
        for (int i = 0; i < 16; i += 4) *(float4*)&kq[i] = *(const float4*)(row + 32 + i);
        float sig = sigmoidf_(dt_c + dtb);
        float ksq = 0.f;
#pragma unroll
        for (int n = 0; n < 8; ++n) ksq = fmaf(kq[n], kq[n], ksq);
        float dts = sig / (1.f + sig * ksq);
        float y = 0.f;
#pragma unroll
        for (int n = 0; n < 8; ++n) {
            float dB = dts * kq[n];
            s[n] = s[n] * (1.f - dB * kq[n]) + x_c * dB;
            y = fmaf(s[n], kq[8 + n], y);
        }
        y = fmaf(Dd, x_c, y);
        float out = y * (z_c * sigmoidf_(z_c));
        xb_y[rbase + (size_t)t * DI] = f2b(out);
    }
}

// ---------------------------------------------------------------- fused TTT prep + 16x16 Gram (validated R19/R20)
__global__ __launch_bounds__(128) void prep_gram_k(const bf16* __restrict__ proj,
                                                   const float* __restrict__ lr_bias,
                                                   const float* __restrict__ tok_idx,
                                                   const float* __restrict__ tok_bias,
                                                   const float* __restrict__ ln_w,
                                                   const float* __restrict__ ln_b,
                                                   float* __restrict__ xkf,
                                                   float* __restrict__ etav,
                                                   float* __restrict__ q0s,
                                                   float* __restrict__ gram) {
    __shared__ __align__(16) float xs[128][68];
    int bh = blockIdx.x >> 4;
    int blk16 = blockIdx.x & 15;
    int tid = threadIdx.x;
    int t = blk16 * 128 + tid;
    int b = bh >> 3, h = bh & 7;
    const bf16* prow = proj + ((size_t)b * L_SEQ + t) * PROJW;
    const bf16* pk = prow + h * 64;
    const bf16* pv = prow + 512 + h * 64;
    const float* lwp = ln_w + h * 64;
    const float* lbp = ln_b + h * 64;
    float* xo = xkf + ((size_t)bh * L_SEQ + t) * 64;
    float q0 = 0.f;
#pragma unroll
    for (int i = 0; i < 64; i += 8) {
        short8v sk = *(const short8v*)(pk + i);
        short8v sv = *(const short8v*)(pv + i);
        float v[8];
#pragma unroll
        for (int j = 0; j < 8; ++j) {
            float xk = us2f((unsigned short)sk[j]);
            float xv = us2f((unsigned short)sv[j]);
            v[j] = xk;
            q0 = fmaf((lbp[i + j] - xv + xk), lwp[i + j], q0);
        }
        float4 lo = make_float4(v[0], v[1], v[2], v[3]);
        float4 hi = make_float4(v[4], v[5], v[6], v[7]);
        *(float4*)(xo + i)     = lo;
        *(float4*)(xo + i + 4) = hi;
        *(float4*)&xs[tid][i]     = lo;
        *(float4*)&xs[tid][i + 4] = hi;
    }
    float eta = sigmoidf_(b2f(prow[1536 + h]) + lr_bias[h]) *
                fmaxf(tok_idx[t] + tok_bias[t], 0.f);
    size_t o = (size_t)bh * L_SEQ + t;
    etav[o] = eta;
    q0s[o]  = q0;
    __syncthreads();
    int chunk = tid >> 4, tt = tid & 15;
    const float* rt = &xs[chunk * 16 + tt][0];
    float* dst = gram + (((size_t)bh * 128 + blk16 * 8 + chunk) * 16 + tt) * 16;
#pragma unroll
    for (int ss = 0; ss < 16; ++ss) {
        const float* rs = &xs[chunk * 16 + ss][0];
        float a0 = 0.f, a1 = 0.f, a2 = 0.f, a3 = 0.f;
#pragma unroll
        for (int j = 0; j < 16; ++j) {
            float4 u = *(const float4*)(rt + 4 * j);
            float4 v = *(const float4*)(rs + 4 * j);
            a0 = fmaf(u.x, v.x, a0); a1 = fmaf(u.y, v.y, a1);
            a2 = fmaf(u.z, v.z, a2); a3 = fmaf(u.w, v.w, a3);
        }
        dst[ss] = (a0 + a1) + (a2 + a3);
    }
}

// ---------------------------------------------------------------- TTT scan body v13: register-resident zb/mu/eg, folded output
__device__ __forceinline__ void ttt_body(const bf16* __restrict__ proj,
                                         const float* __restrict__ xkf,
                                         const float* __restrict__ etav,
                                         const float* __restrict__ q0s,
                                         const float* __restrict__ gram16,
                                         const float* __restrict__ W1,
                                         const float* __restrict__ b1,
                                         const float* __restrict__ ln_w,
                                         const float* __restrict__ ln_b,
                                         bf16* __restrict__ xqw) {
    const int lane = threadIdx.x;
    const int bh = blockIdx.x;
    const int b = bh >> 3, h = bh & 7;

    __shared__ __align__(16) float xkb[2][SB][64];
    __shared__ __align__(16) bf16  xvb[2][SB][64];
    __shared__ __align__(16) float kb[2][4][CHT][CHT];
    __shared__ __align__(16) float sc[2][2][SB];

    float W[64];
#pragma unroll
    for (int f = 0; f < 64; ++f) W[f] = W1[(size_t)(h * 64 + f) * 64 + lane];
    float bvec = b1[h * 64 + lane];
    float lw = ln_w[h * 64 + lane];
    float lb = ln_b[h * 64 + lane];
    float p = lw * lw;

    const float* kfg = xkf + (size_t)bh * L_SEQ * 64;
    const bf16*  pvg = proj + (size_t)b * L_SEQ * PROJW + 512 + h * 64;
    const float* evg = etav + (size_t)bh * L_SEQ;
    const float* qg  = q0s + (size_t)bh * L_SEQ;
    const float* gmg = gram16 + (size_t)bh * 128 * 256;

    // per-sub register state (static indices via full unroll -- no scratch)
    float zb[CHT];   // per-lane matvec result for each token of current sub
    float mu[CHT];   // uniform token means (wave_sum_u returns uniform in all lanes)

    auto stage_async = [&](int c, int bi) {
        const int t0g = c * SB;
#pragma unroll
        for (int i = 0; i < 16; ++i) {
            const float* gp = kfg + (size_t)(t0g + 4 * i) * 64 + lane * 4;
            __builtin_amdgcn_global_load_lds(
                (const __attribute__((address_space(1))) void*)gp,
                (__attribute__((address_space(3))) void*)&xkb[bi][4 * i][0], 16, 0, 0);
        }
#pragma unroll
        for (int i = 0; i < 8; ++i) {
            const bf16* gp = pvg + (size_t)(t0g + 8 * i + (lane >> 3)) * PROJW + (lane & 7) * 8;
            __builtin_amdgcn_global_load_lds(
                (const __attribute__((address_space(1))) void*)gp,
                (__attribute__((address_space(3))) void*)&xvb[bi][8 * i][0], 16, 0, 0);
        }
#pragma unroll
        for (int i = 0; i < 4; ++i) {
            const float* gp = gmg + (size_t)c * 1024 + i * 256 + lane * 4;
            __builtin_amdgcn_global_load_lds(
                (const __attribute__((address_space(1))) void*)gp,
                (__attribute__((address_space(3))) void*)(&kb[bi][0][0][0] + i * 256), 16, 0, 0);
        }
        {
            const float* g0 = evg + t0g + lane;
            __builtin_amdgcn_global_load_lds(
                (const __attribute__((address_space(1))) void*)g0,
                (__attribute__((address_space(3))) void*)&sc[bi][0][0], 4, 0, 0);
            const float* g1 = qg + t0g + lane;
            __builtin_amdgcn_global_load_lds(
                (const __attribute__((address_space(1))) void*)g1,
                (__attribute__((address_space(3))) void*)&sc[bi][1][0], 4, 0, 0);
        }
    };
    auto matvec16 = [&](int nbuf, int nt0) {
#pragma unroll
        for (int t = 0; t < CHT; ++t) {
            const float4* row = (const float4*)&xkb[nbuf][nt0 + t][0];
            float a0 = 0.f, a1 = 0.f, a2 = 0.f, a3 = 0.f;
#pragma unroll
            for (int j = 0; j < 16; ++j) {
                float4 kv = row[j];
                a0 = fmaf(kv.x, W[4 * j + 0], a0);
                a1 = fmaf(kv.y, W[4 * j + 1], a1);
                a2 = fmaf(kv.z, W[4 * j + 2], a2);
                a3 = fmaf(kv.w, W[4 * j + 3], a3);
            }
            float z = (a0 + a1) + (a2 + a3) + bvec;
            zb[t] = z;
            mu[t] = wave_sum_u(z) * 0.015625f;   // uniform in all lanes
        }
    };

    stage_async(0, 0);
    asm volatile("s_waitcnt vmcnt(0)" ::: "memory");
    __builtin_amdgcn_sched_barrier(0);
    matvec16(0, 0);

    bf16* xq = xqw + ((size_t)b * L_SEQ) * DM + h * 64 + lane;

    for (int c = 0; c < NSB; ++c) {
        const int cur = c & 1;
        if (c + 1 < NSB) stage_async(c + 1, 1 - cur);
#pragma unroll 1
        for (int sub = 0; sub < 4; ++sub) {
            const int t0 = sub * CHT;
            float eg[CHT];
            float bacc = 0.f;
            float4 krA, krB, krC, krD;
            {
                const float4* krow = (const float4*)&kb[cur][sub][0][0];
                krA = krow[0]; krB = krow[1]; krC = krow[2]; krD = krow[3];
            }
            float xk_n = xkb[cur][t0 + 0][lane];
            float xv_n = b2f(xvb[cur][t0 + 0][lane]);
            float et_n = sc[cur][0][t0 + 0];
            float q0_n = sc[cur][1][t0 + 0];
#pragma unroll
            for (int t = 0; t < CHT; ++t) {
                float kr[CHT];
                *(float4*)&kr[0]  = krA;
                *(float4*)&kr[4]  = krB;
                *(float4*)&kr[8]  = krC;
                *(float4*)&kr[12] = krD;
                float xk_c = xk_n;
                float xv_c = xv_n;
                float eta  = et_n;
                float q0u  = q0_n;
                float zb_v = zb[t];    // register
                float muv  = mu[t];    // register (uniform)
                // prefetch token t+1 LDS loads before reductions (latency hides)
                if (t + 1 < CHT) {
                    const float4* krow = (const float4*)&kb[cur][sub][t + 1][0];
                    krA = krow[0]; krB = krow[1]; krC = krow[2]; krD = krow[3];
                    xk_n = xkb[cur][t0 + t + 1][lane];
                    xv_n = b2f(xvb[cur][t0 + t + 1][lane]);
                    et_n = sc[cur][0][t0 + t + 1];
                    q0_n = sc[cur][1][t0 + t + 1];
                }

                float gg0 = bacc, gg1 = 0.f, gg2 = 0.f, gg3 = 0.f;
#pragma unroll
                for (int s = 0; s < t; ++s) {
                    if ((s & 3) == 0) gg0 = fmaf(kr[s], eg[s], gg0);
                    else if ((s & 3) == 1) gg1 = fmaf(kr[s], eg[s], gg1);
                    else if ((s & 3) == 2) gg2 = fmaf(kr[s], eg[s], gg2);
                    else gg3 = fmaf(kr[s], eg[s], gg3);
                }
                float z1 = zb_v - ((gg0 + gg1) + (gg2 + gg3));
                float d = z1 - muv;
                float q = (lb - xv_c + xk_c) * lw;
                float S2  = wave_sum_u(d * d);
                float PZ1 = wave_sum_u(p * d);
                float PZ2 = wave_sum_u(p * d * d);
                float Q1  = wave_sum_u(q * d);
                float istd = rsqrtf(S2 * 0.015625f + 1e-6f);
                float A_ = fmaf(istd, PZ1, q0u);
                float Bv = fmaf(istd * istd, PZ2, istd * Q1);
                float xh = d * istd;
                float gxh = fmaf(p, xh, q);
                float grad = (64.f * gxh - A_ - xh * Bv) * (istd * 0.015625f);
                float egt = eta * grad;
                eg[t] = egt;
                bacc += egt;
                // folded output (off the serial critical path)
                float z1q = fmaf(-eta * (kr[t] + 1.f), grad, z1);
                float dq = z1q - muv;
                float SQ = wave_sum_u(dq * dq);
                float istd2 = rsqrtf(SQ * 0.015625f + 1e-6f);
                float outv = fmaf(lw, dq * istd2, xk_c + lb);
                xq[(size_t)(c * SB + t0 + t) * DM] = f2b(outv);
            }
            bool last = (c == NSB - 1) && (sub == 3);
            if (!last) {
                // W update from eg registers (static indices, full unroll)
#pragma unroll
                for (int s = 0; s < CHT; ++s) {
                    float egs = eg[s];
                    const float4* row = (const float4*)&xkb[cur][t0 + s][0];
#pragma unroll
                    for (int j = 0; j < 16; ++j) {
                        float4 kv = row[j];
                        W[4 * j + 0] = fmaf(-egs, kv.x, W[4 * j + 0]);
                        W[4 * j + 1] = fmaf(-egs, kv.y, W[4 * j + 1]);
                        W[4 * j + 2] = fmaf(-egs, kv.z, W[4 * j + 2]);
                        W[4 * j + 3] = fmaf(-egs, kv.w, W[4 * j + 3]);
                    }
                }
                bvec -= bacc;
                int nbuf = cur, nt0 = t0 + CHT;
                if (sub == 3) {
                    nbuf = 1 - cur; nt0 = 0;
                    asm volatile("s_waitcnt vmcnt(0)" ::: "memory");
                    __builtin_amdgcn_sched_barrier(0);
                }
                matvec16(nbuf, nt0);
            }
        }
    }
}

// ---------------------------------------------------------------- hetero: blocks 0-31 ttt, blocks 32+ fused zlg GEMM (N=1536)
__global__ __launch_bounds__(256) void hetero_k(const bf16* __restrict__ proj,
                                                const float* __restrict__ xkf,
                                                const float* __restrict__ etav,
                                                const float* __restrict__ q0s,
                                                const float* __restrict__ gram16,
                                                const float* __restrict__ W1,
                                                const float* __restrict__ b1,
                                                const float* __restrict__ ln_w,
                                                const float* __restrict__ ln_b,
                                                bf16* __restrict__ xqw,
                                                const bf16* __restrict__ hred,
                                                const bf16* __restrict__ wcat,
                                                bf16* __restrict__ zl,
                                                bf16* __restrict__ gq,
                                                bf16* __restrict__ gk) {
    if (blockIdx.x < 32) {
        if (threadIdx.x < 64)
            ttt_body(proj, xkf, etav, q0s, gram16, W1, b1, ln_w, ln_b, xqw);
        return;
    }
    __shared__ __align__(16) bf16 As[128 * 48];
    __shared__ __align__(16) bf16 Ws[128 * 48];
    const int bidx = blockIdx.x - 32;
    const int tid = threadIdx.x;
    const int lane = tid & 63;
    const int widx = tid >> 6;
    const int bm = (bidx & 63) * 128;
    const int bn = (bidx >> 6) * 128;
    const int wr = (widx >> 1) * 64;
    const int wc = (widx & 1) * 64;

    f32x4 acc[4][4];
#pragma unroll
    for (int i = 0; i < 4; ++i)
#pragma unroll
        for (int j = 0; j < 4; ++j) acc[i][j] = (f32x4){0.f, 0.f, 0.f, 0.f};

    const int r0 = tid >> 2;
    const int c0 = tid & 3;
    const int frow = lane & 15;
    const int fk = (lane >> 4) * 8;

    const bf16* pa0 = hred + (size_t)(bm + r0) * DM + c0 * 8;
    const bf16* pa1 = hred + (size_t)(bm + r0 + 64) * DM + c0 * 8;
    const bf16* pb0 = wcat + (size_t)(bn + r0) * DM + c0 * 8;
    const bf16* pb1 = wcat + (size_t)(bn + r0 + 64) * DM + c0 * 8;

    for (int k0 = 0; k0 < DM; k0 += 32) {
        short8v a0 = *(const short8v*)(pa0 + k0);
        short8v a1 = *(const short8v*)(pa1 + k0);
        short8v b0 = *(const short8v*)(pb0 + k0);
        short8v b1 = *(const short8v*)(pb1 + k0);
        __syncthreads();
        *(short8v*)&As[r0 * 48 + c0 * 8] = a0;
        *(short8v*)&As[(r0 + 64) * 48 + c0 * 8] = a1;
        *(short8v*)&Ws[r0 * 48 + c0 * 8] = b0;
        *(short8v*)&Ws[(r0 + 64) * 48 + c0 * 8] = b1;
        __syncthreads();
        short8v af[4], bg[4];
#pragma unroll
        for (int mi = 0; mi < 4; ++mi)
            af[mi] = *(const short8v*)&As[(wr + mi * 16 + frow) * 48 + fk];
#pragma unroll
        for (int ni = 0; ni < 4; ++ni)
            bg[ni] = *(const short8v*)&Ws[(wc + ni * 16 + frow) * 48 + fk];
#pragma unroll
        for (int mi = 0; mi < 4; ++mi)
#pragma unroll
            for (int ni = 0; ni < 4; ++ni)
                acc[mi][ni] = __builtin_amdgcn_mfma_f32_16x16x32_bf16(
                    af[mi], bg[ni], acc[mi][ni], 0, 0, 0);
    }

#pragma unroll
    for (int ni = 0; ni < 4; ++ni) {
        int col = bn + wc + ni * 16 + (lane & 15);
        int buf = col >> 9;
        int lc = col & 511;
        bf16* Cb = (buf == 0) ? zl : (buf == 1) ? gq : gk;
#pragma unroll
        for (int mi = 0; mi < 4; ++mi) {
            int rbase = bm + wr + mi * 16 + (lane >> 4) * 4;
#pragma unroll
            for (int r = 0; r < 4; ++r)
                Cb[(size_t)(rbase + r) * 512 + lc] = f2b(acc[mi][ni][r]);
        }
    }
}

// ---------------------------------------------------------------- post-norm + gelu gate
__global__ __launch_bounds__(256) void gated_k(const bf16* __restrict__ xqw,
                                               const bf16* __restrict__ proj,
                                               const float* __restrict__ pnw,
                                               const float* __restrict__ pnb,
                                               bf16* __restrict__ gated) {
    int r = blockIdx.x, tid = threadIdx.x;
    const bf16* row = xqw + (size_t)r * DM;
    float v0 = b2f(row[tid]), v1 = b2f(row[tid + 256]);
    float s = v0 + v1, q = v0 * v0 + v1 * v1;
#pragma unroll
    for (int off = 32; off; off >>= 1) {
        s += __shfl_xor(s, off);
        q += __shfl_xor(q, off);
    }
    __shared__ float sm[8];
    if ((tid & 63) == 0) { sm[tid >> 6] = s; sm[4 + (tid >> 6)] = q; }
    __syncthreads();
    s = sm[0] + sm[1] + sm[2] + sm[3];
    q = sm[4] + sm[5] + sm[6] + sm[7];
    float mu = s * (1.f / 512.f);
    float var = q * (1.f / 512.f) - mu * mu;
    float istd = rsqrtf(var + 1e-5f);
    const bf16* grow = proj + (size_t)r * PROJW + 1024;
    bf16* orow = gated + (size_t)r * DM;
#pragma unroll
    for (int e = 0; e < 2; ++e) {
        int c = tid + e * 256;
        float xv = (e == 0) ? v0 : v1;
        float nv = (xv - mu) * istd * pnw[c] + pnb[c];
        float g = b2f(grow[c]);
        float gg = 0.5f * g * (1.f + tanhf(0.7978845608028654f * (g + 0.044715f * g * g * g)));
        orow[c] = f2b(gg * nv);
    }
}

// ---------------------------------------------------------------- gq mean (bf16 input), two-phase
__global__ __launch_bounds__(256) void mean1_k(const bf16* __restrict__ gq,
                                               float* __restrict__ partial) {
    int blk = blockIdx.x;
    int b = blk >> 4, c = blk & 15;
    int tid = threadIdx.x;
    const bf16* p = gq + ((size_t)b * L_SEQ + c * 128) * DM + tid * 2;
    float a0 = 0.f, a1 = 0.f;
    for (int l = 0; l < 128; ++l) {
        ushort2 u = *(const ushort2*)(p + (size_t)l * DM);
        a0 += us2f(u.x); a1 += us2f(u.y);
    }
    partial[(size_t)blk * DM + tid * 2]     = a0;
    partial[(size_t)blk * DM + tid * 2 + 1] = a1;
}
__global__ __launch_bounds__(256) void mean2_k(const float* __restrict__ partial,
                                               float* __restrict__ gqm) {
    int t = blockIdx.x * 256 + threadIdx.x;
    if (t >= 2048) return;
    int b = t >> 9, d = t & 511;
    float acc = 0.f;
#pragma unroll
    for (int c = 0; c < 16; ++c) acc += partial[(size_t)(b * 16 + c) * DM + d];
    gqm[t] = acc * (1.f / 2048.f);
}

// ---------------------------------------------------------------- gain + final mix (bf16 z inputs)
__global__ __launch_bounds__(64) void final_k(const bf16* __restrict__ zl,
                                              const bf16* __restrict__ zt,
                                              const bf16* __restrict__ gk,
                                              const float* __restrict__ gqm,
                                              const float* __restrict__ alpha,
                                              const float* __restrict__ beta,
                                              float* __restrict__ out,
                                              float* __restrict__ gain_out) {
    int r = blockIdx.x;
    int lane = threadIdx.x;
    int b = r >> 11;
    const bf16* gkr = gk + (size_t)r * DM;
    const float* gmb = gqm + b * DM;
    float acc = 0.f;
#pragma unroll
    for (int i = 0; i < 8; ++i) acc = fmaf(gmb[lane + 64 * i], b2f(gkr[lane + 64 * i]), acc);
#pragma unroll
    for (int off = 32; off; off >>= 1) acc += __shfl_xor(acc, off);
    float score = acc * 0.04419417382415922f;
    float g = sigmoidf_(alpha[0] * score + beta[0]);
    g = fminf(g, 0.55f);
    if (lane == 0) gain_out[r] = g;
    const bf16* zlr = zl + (size_t)r * DM;
    const bf16* ztr = zt + (size_t)r * DM;
    float* orow = out + (size_t)r * DM;
#pragma unroll
    for (int i = 0; i < 8; ++i) {
        int c = lane + 64 * i;
        float a = b2f(zlr[c]);
        orow[c] = a + g * (b2f(ztr[c]) - a);
    }
}

// ---------------------------------------------------------------- host launcher

extern "C" void kernel_launch(void* const* d_in, const int* in_sizes, int n_in,
                              void* d_out, int out_size, void* d_ws, size_t ws_size,
                              hipStream_t stream) {
    const float* x           = (const float*)d_in[0];
    const float* norm_w      = (const float*)d_in[1];
    const float* in_proj_w   = (const float*)d_in[2];
    const float* conv_w      = (const float*)d_in[3];
    const float* conv_b      = (const float*)d_in[4];
    const float* x_proj_w    = (const float*)d_in[5];
    const float* dt_head_w   = (const float*)d_in[6];
    const float* dt_head_b   = (const float*)d_in[7];
    const float* Dvec        = (const float*)d_in[8];
    const float* reduce_w    = (const float*)d_in[9];
    const float* q_net_w     = (const float*)d_in[10];
    const float* gain_q_w    = (const float*)d_in[11];
    const float* gain_k_w    = (const float*)d_in[12];
    const float* alpha       = (const float*)d_in[13];
    const float* beta        = (const float*)d_in[14];
    const float* qkv_w       = (const float*)d_in[15];
    const float* qkv_b       = (const float*)d_in[16];
    const float* ttt_lr_bias = (const float*)d_in[17];
    const float* W1          = (const float*)d_in[18];
    const float* b1          = (const float*)d_in[19];
    const float* token_idx   = (const float*)d_in[20];
    const float* token_bias  = (const float*)d_in[21];
    const float* ttt_ln_w    = (const float*)d_in[22];
    const float* ttt_ln_b    = (const float*)d_in[23];
    const float* post_norm_w = (const float*)d_in[24];
    const float* post_norm_b = (const float*)d_in[25];
    const float* wo_w        = (const float*)d_in[26];
    const float* wo_b        = (const float*)d_in[27];

    const size_t SZ_ROWDM = (size_t)NROWS * DM;
    const size_t MB = 1024u * 1024u;
    const size_t KB = 1024u;
    char* base = (char*)d_ws;

    float* out_p  = (float*)d_out;
    float* res_p  = out_p + SZ_ROWDM;
    float* gain_p = out_p + 2 * SZ_ROWDM;

    if (ws_size < 116 * MB) {
        copy4_k<<<(int)(SZ_ROWDM / 4 / 256), 256, 0, stream>>>(
            (const float4*)x, (float4*)res_p, (int)(SZ_ROWDM / 4));
        return;
    }

    // ---- workspace layout; lifetimes identical to validated R20
    bf16*  inpb   = (bf16*)base;                    // in_proj bf16 [0,6)
    bf16*  xpb    = (bf16*)(base + 6 * MB);         // [6,6.6)
    float* lpq    = (float*)base;                   // [0,12.58)
    bf16*  redb   = (bf16*)base;                    // [0,3)
    bf16*  qkvb   = (bf16*)(base + 3 * MB);         // [3,4.51)
    bf16*  wob16  = (bf16*)(base + 4 * MB + 768 * KB);
    bf16*  wcat   = (bf16*)(base + 114 * MB + 512 * KB);
    bf16*  xn     = (bf16*)(base + 7 * MB);
    bf16*  h_red  = xn;
    bf16*  cside  = (bf16*)(base + 7 * MB);
    bf16*  bufX   = (bf16*)(base + 16 * MB);
    bf16*  bufZ   = (bf16*)(base + 64 * MB);
    float* xdbl   = (float*)(base + 112 * MB);
    float* gqm    = (float*)(base + 113 * MB + 512 * KB);
    float* mpart  = (float*)(base + 114 * MB);
    bf16*  proj   = bufX;
    bf16*  xqw    = bufZ;
    bf16*  zl     = (bf16*)(base + 72 * MB);
    bf16*  gq     = (bf16*)(base + 80 * MB);
    float* gramb  = (float*)(base + 88 * MB);
    bf16*  gk     = (bf16*)(base + 92 * MB);
    bf16*  zttt   = (bf16*)(base + 100 * MB);
    bf16*  gated  = (bf16*)(base + 104 * MB);
    bf16*  chid   = (bf16*)(base + 42 * MB);
    float* xkf    = (float*)(base + 42 * MB);
    float* etav   = (float*)(base + 58 * MB);
    float* q0s    = (float*)(base + 58 * MB + 512 * KB);

    // 1. rmsnorm + residual
    rmsnorm_res_k<<<NROWS, 256, 0, stream>>>(x, norm_w, xn, res_p);

    // 2. in_proj cvt + merged GEMM (N=6144 -> bufX|bufZ)
    cvt_k<<<(2 * DI * DM / 4 + 255) / 256, 256, 0, stream>>>(in_proj_w, inpb, 2 * DI * DM / 4);
    {
        dim3 g(NROWS / 128, 2 * DI / 128);
        gemm_inproj<<<g, 256, 0, stream>>>(xn, inpb, bufX, bufZ);
    }

    // 3. wcat cvt
    cvt3_k<<<(3 * 65536 + 255) / 256, 256, 0, stream>>>(q_net_w, gain_q_w, gain_k_w, wcat);

    // 4. conv
    conv_boundary_k<<<((L_SEQ / CTILE - 1) * 2 * BDI) / 256, 256, 0, stream>>>(bufX, cside);
    conv_tile_k<<<((L_SEQ / CTILE) * BDI) / 256, 256, 0, stream>>>(bufX, cside, conv_w, conv_b);

    // 5. x_proj cvt + gemm
    cvt_k<<<(48 * DI / 4 + 255) / 256, 256, 0, stream>>>(x_proj_w, xpb, 48 * DI / 4);
    {
        dim3 g(NROWS / 128, 1);
        gemm_mfma<0, float><<<g, 256, 0, stream>>>(bufX, DI, xpb, DI, nullptr, xdbl, 48, 48, DI);
    }

    // 6. longhorn chunked scan (lpq over dead in_proj/xpb scratch)
    longhorn_p1<<<(NLCH * BDI) / 256, 256, 0, stream>>>(bufX, xdbl, dt_head_w, dt_head_b, lpq);
    longhorn_p2<<<BDI / 256, 256, 0, stream>>>(lpq);
    longhorn_p3<<<(NLCH * BDI) / 256, 256, 0, stream>>>(bufX, bufZ, xdbl, dt_head_w,
                                                        dt_head_b, Dvec, lpq);

    // 7. reduce/qkv/wo cvt (over dead lpq)
    cvt_rqw_k<<<(C_RED + C_QKV + C_WO + 255) / 256, 256, 0, stream>>>(
        reduce_w, qkv_w, wo_w, redb, qkvb, wob16);

    // 8. reduce -> h_red
    {
        dim3 g(NROWS / 128, DM / 128);
        gemm_mfma<0, bf16><<<g, 256, 0, stream>>>(bufX, DI, redb, DI, nullptr, h_red, DM, DM, DI);
    }

    // 9. qkv -> proj
    {
        dim3 g(NROWS / 128, (PROJW + 127) / 128);
        gemm_mfma<1, bf16><<<g, 256, 0, stream>>>(h_red, DM, qkvb, DM, qkv_b, proj, PROJW, PROJW, DM);
    }

    // 10. fused prep+gram
    prep_gram_k<<<32 * 16, 128, 0, stream>>>(proj, ttt_lr_bias, token_idx, token_bias,
                                             ttt_ln_w, ttt_ln_b, xkf, etav, q0s, gramb);

    // 11. hetero: ttt + zl/gq/gk GEMM overlapped
    hetero_k<<<32 + 768, 256, 0, stream>>>(proj, xkf, etav, q0s, gramb, W1, b1,
                                           ttt_ln_w, ttt_ln_b, xqw,
                                           h_red, wcat, zl, gq, gk);

    // 12. gated
    gated_k<<<NROWS, 256, 0, stream>>>(xqw, proj, post_norm_w, post_norm_b, gated);

    // 13. wo -> chid ; zttt = chid @ q_net (wcat rows 0-511)
    {
        dim3 g(NROWS / 128, DM / 128);
        gemm_mfma<1, bf16><<<g, 256, 0, stream>>>(gated, DM, wob16, DM, wo_b, chid, DM, DM, DM);
        gemm_mfma<0, bf16><<<g, 256, 0, stream>>>(chid, DM, wcat, DM, nullptr, zttt, DM, DM, DM);
    }

    // 14. gq mean + final
    mean1_k<<<64, 256, 0, stream>>>(gq, mpart);
    mean2_k<<<8, 256, 0, stream>>>(mpart, gqm);
    final_k<<<NROWS, 64, 0, stream>>>(zl, zttt, gk, gqm, alpha, beta, out_p, gain_p);
}

// Round 22
// 3409.829 us; speedup vs baseline: 1.3628x; 1.3628x over previous
//
#include <hip/hip_runtime.h>
#include <hip/hip_bf16.h>
#include <cstdint>
#include <cstddef>

#define L_SEQ 2048
#define BATCH 4
#define DM    512
#define DI    3072
#define NROWS (BATCH * L_SEQ)   // 8192
#define PROJW 1544              // 3*512 + 8
#define CTILE 16
#define BDI   (BATCH * DI)      // 12288
#define CHT   16                // ttt serial sub-chunk = staging unit
#define NST   (L_SEQ / CHT)     // 128 stages
#define LCH   128               // longhorn chunk tokens (R17-proven)
#define NLCH  (L_SEQ / LCH)     // 16

using bf16 = __hip_bfloat16;

typedef __attribute__((ext_vector_type(8))) short short8v;
typedef __attribute__((ext_vector_type(4))) float f32x4;

// ---------------------------------------------------------------- utilities

__device__ __forceinline__ float sigmoidf_(float x) { return 1.f / (1.f + __expf(-x)); }
__device__ __forceinline__ float us2f(unsigned int u) {
    union { unsigned int i; float f; } c; c.i = u << 16; return c.f;
}
__device__ __forceinline__ bf16  f2b(float f) { return __float2bfloat16(f); }
__device__ __forceinline__ float b2f(bf16 v)  { return __bfloat162float(v); }
__device__ __forceinline__ void st1(float* p, float v) { *p = v; }
__device__ __forceinline__ void st1(bf16* p, float v)  { *p = f2b(v); }

// DPP-based wave64 sum -> uniform value (validated R4-R20)
template <int CTRL>
__device__ __forceinline__ float dppadd_(float x) {
    int s = __builtin_amdgcn_update_dpp(0, __builtin_bit_cast(int, x), CTRL, 0xF, 0xF, true);
    return x + __builtin_bit_cast(float, s);
}
__device__ __forceinline__ float wave_sum_u(float x) {
    x = dppadd_<0x111>(x);
    x = dppadd_<0x112>(x);
    x = dppadd_<0x114>(x);
    x = dppadd_<0x118>(x);
    x = dppadd_<0x142>(x);
    x = dppadd_<0x143>(x);
    return __builtin_bit_cast(float,
        __builtin_amdgcn_readlane(__builtin_bit_cast(int, x), 63));
}

// ---------------------------------------------------------------- residual copy (ws-too-small fallback only)
__global__ __launch_bounds__(256) void copy4_k(const float4* __restrict__ in,
                                               float4* __restrict__ out, int n) {
    int i = blockIdx.x * 256 + threadIdx.x;
    if (i < n) out[i] = in[i];
}

// ---------------------------------------------------------------- f32 -> bf16 weight convert
__global__ __launch_bounds__(256) void cvt_k(const float* __restrict__ in,
                                             bf16* __restrict__ out, int n4) {
    int i = blockIdx.x * 256 + threadIdx.x;
    if (i >= n4) return;
    float4 v = ((const float4*)in)[i];
    out[4 * i + 0] = f2b(v.x);
    out[4 * i + 1] = f2b(v.y);
    out[4 * i + 2] = f2b(v.z);
    out[4 * i + 3] = f2b(v.w);
}

// concat 3x [512][512] f32 -> bf16 wcat[1536][512]
__global__ __launch_bounds__(256) void cvt3_k(const float* __restrict__ a,
                                              const float* __restrict__ b,
                                              const float* __restrict__ c,
                                              bf16* __restrict__ out) {
    int i = blockIdx.x * 256 + threadIdx.x;
    const int seg = 512 * 512 / 4;
    if (i >= 3 * seg) return;
    const float* src = (i < seg) ? a : (i < 2 * seg) ? b : c;
    int j = (i < seg) ? i : (i < 2 * seg) ? i - seg : i - 2 * seg;
    float4 v = ((const float4*)src)[j];
    bf16* o = out + (size_t)i * 4;
    o[0] = f2b(v.x); o[1] = f2b(v.y); o[2] = f2b(v.z); o[3] = f2b(v.w);
}

// merged cvt: reduce | qkv | wo  (run after longhorn, over dead lpq region)
#define C_RED  393216                  // reduce f4 units
#define C_QKV  197632                  // qkv
#define C_WO   65536                   // wo
__global__ __launch_bounds__(256) void cvt_rqw_k(const float* __restrict__ reduce_w,
                                                 const float* __restrict__ qkv_w,
                                                 const float* __restrict__ wo_w,
                                                 bf16* __restrict__ redb,
                                                 bf16* __restrict__ qkvb,
                                                 bf16* __restrict__ wob) {
    int i = blockIdx.x * 256 + threadIdx.x;
    const float* src;
    bf16* dst;
    int j;
    if (i < C_RED)                     { src = reduce_w; dst = redb; j = i; }
    else if (i < C_RED + C_QKV)        { src = qkv_w;    dst = qkvb; j = i - C_RED; }
    else if (i < C_RED + C_QKV + C_WO) { src = wo_w;     dst = wob;  j = i - C_RED - C_QKV; }
    else return;
    float4 v = ((const float4*)src)[j];
    bf16* o = dst + (size_t)j * 4;
    o[0] = f2b(v.x); o[1] = f2b(v.y); o[2] = f2b(v.z); o[3] = f2b(v.w);
}

// ---------------------------------------------------------------- rmsnorm + residual copy fused
__global__ __launch_bounds__(256) void rmsnorm_res_k(const float* __restrict__ x,
                                                     const float* __restrict__ w,
                                                     bf16* __restrict__ xn,
                                                     float* __restrict__ res) {
    int r = blockIdx.x, tid = threadIdx.x;
    const float* row = x + (size_t)r * DM;
    float v0 = row[tid], v1 = row[tid + 256];
    float q = v0 * v0 + v1 * v1;
#pragma unroll
    for (int off = 32; off; off >>= 1) q += __shfl_xor(q, off);
    __shared__ float sm[4];
    if ((tid & 63) == 0) sm[tid >> 6] = q;
    __syncthreads();
    q = sm[0] + sm[1] + sm[2] + sm[3];
    float scale = rsqrtf(q * (1.f / 512.f) + 1e-5f);
    bf16* orow = xn + (size_t)r * DM;
    float* rrow = res + (size_t)r * DM;
    orow[tid]       = f2b(v0 * scale * w[tid]);
    orow[tid + 256] = f2b(v1 * scale * w[tid + 256]);
    rrow[tid]       = v0;
    rrow[tid + 256] = v1;
}

// ---------------------------------------------------------------- bf16 MFMA GEMM (validated R3)
template <int BIAS, typename TC>
__global__ __launch_bounds__(256) void gemm_mfma(const bf16* __restrict__ A, int lda,
                                                 const bf16* __restrict__ Wb, int ldw,
                                                 const float* __restrict__ bias,
                                                 TC* __restrict__ C, int ldc,
                                                 int N, int K) {
    __shared__ __align__(16) bf16 As[128 * 48];
    __shared__ __align__(16) bf16 Ws[128 * 48];
    const int tid = threadIdx.x;
    const int lane = tid & 63;
    const int widx = tid >> 6;
    const int bm = blockIdx.x * 128;
    const int bn = blockIdx.y * 128;
    const int wr = (widx >> 1) * 64;
    const int wc = (widx & 1) * 64;

    f32x4 acc[4][4];
#pragma unroll
    for (int i = 0; i < 4; ++i)
#pragma unroll
        for (int j = 0; j < 4; ++j) acc[i][j] = (f32x4){0.f, 0.f, 0.f, 0.f};

    const int r0 = tid >> 2;
    const int c0 = tid & 3;
    const int frow = lane & 15;
    const int fk = (lane >> 4) * 8;

    int n0 = bn + r0;       if (n0 > N - 1) n0 = N - 1;
    int n1 = bn + r0 + 64;  if (n1 > N - 1) n1 = N - 1;
    const bf16* pa0 = A + (size_t)(bm + r0) * lda + c0 * 8;
    const bf16* pa1 = A + (size_t)(bm + r0 + 64) * lda + c0 * 8;
    const bf16* pb0 = Wb + (size_t)n0 * ldw + c0 * 8;
    const bf16* pb1 = Wb + (size_t)n1 * ldw + c0 * 8;

    for (int k0 = 0; k0 < K; k0 += 32) {
        short8v a0 = *(const short8v*)(pa0 + k0);
        short8v a1 = *(const short8v*)(pa1 + k0);
        short8v b0 = *(const short8v*)(pb0 + k0);
        short8v b1 = *(const short8v*)(pb1 + k0);
        __syncthreads();
        *(short8v*)&As[r0 * 48 + c0 * 8] = a0;
        *(short8v*)&As[(r0 + 64) * 48 + c0 * 8] = a1;
        *(short8v*)&Ws[r0 * 48 + c0 * 8] = b0;
        *(short8v*)&Ws[(r0 + 64) * 48 + c0 * 8] = b1;
        __syncthreads();
        short8v af[4], bg[4];
#pragma unroll
        for (int mi = 0; mi < 4; ++mi)
            af[mi] = *(const short8v*)&As[(wr + mi * 16 + frow) * 48 + fk];
#pragma unroll
        for (int ni = 0; ni < 4; ++ni)
            bg[ni] = *(const short8v*)&Ws[(wc + ni * 16 + frow) * 48 + fk];
#pragma unroll
        for (int mi = 0; mi < 4; ++mi)
#pragma unroll
            for (int ni = 0; ni < 4; ++ni)
                acc[mi][ni] = __builtin_amdgcn_mfma_f32_16x16x32_bf16(
                    af[mi], bg[ni], acc[mi][ni], 0, 0, 0);
    }

#pragma unroll
    for (int ni = 0; ni < 4; ++ni) {
        int col = bn + wc + ni * 16 + (lane & 15);
        if (col < N) {
            float bz = BIAS ? bias[col] : 0.f;
#pragma unroll
            for (int mi = 0; mi < 4; ++mi) {
                int rbase = bm + wr + mi * 16 + (lane >> 4) * 4;
#pragma unroll
                for (int r = 0; r < 4; ++r) {
                    float v = acc[mi][ni][r] + bz;
                    st1(&C[(size_t)(rbase + r) * ldc + col], v);
                }
            }
        }
    }
}

// ---------------------------------------------------------------- merged in_proj GEMM: N=6144, split C (bufX | bufZ)
__global__ __launch_bounds__(256) void gemm_inproj(const bf16* __restrict__ A,
                                                   const bf16* __restrict__ Wb,
                                                   bf16* __restrict__ cx,
                                                   bf16* __restrict__ cz) {
    __shared__ __align__(16) bf16 As[128 * 48];
    __shared__ __align__(16) bf16 Ws[128 * 48];
    const int tid = threadIdx.x;
    const int lane = tid & 63;
    const int widx = tid >> 6;
    const int bm = blockIdx.x * 128;
    const int bn = blockIdx.y * 128;
    const int wr = (widx >> 1) * 64;
    const int wc = (widx & 1) * 64;

    f32x4 acc[4][4];
#pragma unroll
    for (int i = 0; i < 4; ++i)
#pragma unroll
        for (int j = 0; j < 4; ++j) acc[i][j] = (f32x4){0.f, 0.f, 0.f, 0.f};

    const int r0 = tid >> 2;
    const int c0 = tid & 3;
    const int frow = lane & 15;
    const int fk = (lane >> 4) * 8;

    const bf16* pa0 = A + (size_t)(bm + r0) * DM + c0 * 8;
    const bf16* pa1 = A + (size_t)(bm + r0 + 64) * DM + c0 * 8;
    const bf16* pb0 = Wb + (size_t)(bn + r0) * DM + c0 * 8;
    const bf16* pb1 = Wb + (size_t)(bn + r0 + 64) * DM + c0 * 8;

    for (int k0 = 0; k0 < DM; k0 += 32) {
        short8v a0 = *(const short8v*)(pa0 + k0);
        short8v a1 = *(const short8v*)(pa1 + k0);
        short8v b0 = *(const short8v*)(pb0 + k0);
        short8v b1 = *(const short8v*)(pb1 + k0);
        __syncthreads();
        *(short8v*)&As[r0 * 48 + c0 * 8] = a0;
        *(short8v*)&As[(r0 + 64) * 48 + c0 * 8] = a1;
        *(short8v*)&Ws[r0 * 48 + c0 * 8] = b0;
        *(short8v*)&Ws[(r0 + 64) * 48 + c0 * 8] = b1;
        __syncthreads();
        short8v af[4], bg[4];
#pragma unroll
        for (int mi = 0; mi < 4; ++mi)
            af[mi] = *(const short8v*)&As[(wr + mi * 16 + frow) * 48 + fk];
#pragma unroll
        for (int ni = 0; ni < 4; ++ni)
            bg[ni] = *(const short8v*)&Ws[(wc + ni * 16 + frow) * 48 + fk];
#pragma unroll
        for (int mi = 0; mi < 4; ++mi)
#pragma unroll
            for (int ni = 0; ni < 4; ++ni)
                acc[mi][ni] = __builtin_amdgcn_mfma_f32_16x16x32_bf16(
                    af[mi], bg[ni], acc[mi][ni], 0, 0, 0);
    }

    bf16* Cb = (bn < DI) ? cx : cz;
    const int coff = (bn < DI) ? 0 : DI;
#pragma unroll
    for (int ni = 0; ni < 4; ++ni) {
        int col = bn + wc + ni * 16 + (lane & 15) - coff;
#pragma unroll
        for (int mi = 0; mi < 4; ++mi) {
            int rbase = bm + wr + mi * 16 + (lane >> 4) * 4;
#pragma unroll
            for (int r = 0; r < 4; ++r)
                Cb[(size_t)(rbase + r) * DI + col] = f2b(acc[mi][ni][r]);
        }
    }
}

// ---------------------------------------------------------------- conv: boundary row copy
__global__ __launch_bounds__(256) void conv_boundary_k(const bf16* __restrict__ x,
                                                       bf16* __restrict__ side) {
    int idx = blockIdx.x * 256 + threadIdx.x;
    const int total = (L_SEQ / CTILE - 1) * 2 * BDI;
    if (idx >= total) return;
    int col = idx % BDI;
    int rr = idx / BDI;
    int tile = (rr >> 1) + 1;
    int r = rr & 1;
    int b = col / DI, d = col % DI;
    int l = tile * CTILE - 2 + r;
    side[idx] = x[((size_t)b * L_SEQ + l) * DI + d];
}

// ---------------------------------------------------------------- conv tile: causal depthwise conv3 + silu
__global__ __launch_bounds__(256) void conv_tile_k(bf16* __restrict__ x,
                                                   const bf16* __restrict__ side,
                                                   const float* __restrict__ cw,
                                                   const float* __restrict__ cb) {
    int idx = blockIdx.x * 256 + threadIdx.x;
    const int total = (L_SEQ / CTILE) * BDI;
    if (idx >= total) return;
    int col = idx % BDI;
    int tile = idx / BDI;
    int b = col / DI, d = col % DI;
    float w0 = cw[3 * d], w1 = cw[3 * d + 1], w2 = cw[3 * d + 2], bias = cb[d];
    size_t base = ((size_t)b * L_SEQ + tile * CTILE) * DI + d;
    float xm2, xm1;
    if (tile == 0) { xm2 = 0.f; xm1 = 0.f; }
    else {
        const bf16* sp = side + ((size_t)(tile - 1) * 2) * BDI + col;
        xm2 = b2f(sp[0]);
        xm1 = b2f(sp[BDI]);
    }
    float cur = b2f(x[base]);
#pragma unroll
    for (int i = 0; i < CTILE; ++i) {
        float nxt = (i + 1 < CTILE) ? b2f(x[base + (size_t)(i + 1) * DI]) : 0.f;
        float a = bias + w0 * xm2 + w1 * xm1 + w2 * cur;
        x[base + (size_t)i * DI] = f2b(a * sigmoidf_(a));
        xm2 = xm1; xm1 = cur; cur = nxt;
    }
}

// ---------------------------------------------------------------- longhorn chunked scan (validated R13; LCH=128)
__global__ __launch_bounds__(256) void longhorn_p1(const bf16* __restrict__ xb,
                                                   const float* __restrict__ xdbl,
                                                   const float* __restrict__ dtw,
                                                   const float* __restrict__ dtb_v,
                                                   float* __restrict__ pq) {
    int idx = blockIdx.x * 256 + threadIdx.x;
    int ch = idx / BDI;
    int col = idx % BDI;
    int b = col / DI, d = col % DI;
    float w32[32];
#pragma unroll
    for (int i = 0; i < 32; ++i) w32[i] = dtw[d * 32 + i];
    float dtb = dtb_v[d];
    float P[8] = {1.f, 1.f, 1.f, 1.f, 1.f, 1.f, 1.f, 1.f};
    float Q[8] = {0.f, 0.f, 0.f, 0.f, 0.f, 0.f, 0.f, 0.f};
    size_t rbase = ((size_t)b * L_SEQ + ch * LCH) * DI + d;
    const float* xdb = xdbl + ((size_t)b * L_SEQ + ch * LCH) * 48;

    float xv = b2f(xb[rbase]);
    for (int t = 0; t < LCH; ++t) {
        float x_c = xv;
        if (t + 1 < LCH) xv = b2f(xb[rbase + (size_t)(t + 1) * DI]);
        const float* row = xdb + (size_t)t * 48;
        float dt_c = 0.f;
#pragma unroll
        for (int i = 0; i < 32; i += 4) {
            float4 r4 = *(const float4*)(row + i);
            dt_c = fmaf(r4.x, w32[i + 0], dt_c);
            dt_c = fmaf(r4.y, w32[i + 1], dt_c);
            dt_c = fmaf(r4.z, w32[i + 2], dt_c);
            dt_c = fmaf(r4.w, w32[i + 3], dt_c);
        }
        float kq[8];
#pragma unroll
        for (int i = 0; i < 8; i += 4) *(float4*)&kq[i] = *(const float4*)(row + 32 + i);
        float sig = sigmoidf_(dt_c + dtb);
        float ksq = 0.f;
#pragma unroll
        for (int n = 0; n < 8; ++n) ksq = fmaf(kq[n], kq[n], ksq);
        float dts = sig / (1.f + sig * ksq);
#pragma unroll
        for (int n = 0; n < 8; ++n) {
            float dB = dts * kq[n];
            float a = 1.f - dB * kq[n];
            P[n] *= a;
            Q[n] = fmaf(Q[n], a, x_c * dB);
        }
    }
    float* o = pq + (size_t)idx * 16;
#pragma unroll
    for (int n = 0; n < 8; n += 4) {
        *(float4*)(o + n)     = make_float4(P[n], P[n + 1], P[n + 2], P[n + 3]);
        *(float4*)(o + 8 + n) = make_float4(Q[n], Q[n + 1], Q[n + 2], Q[n + 3]);
    }
}

__global__ __launch_bounds__(256) void longhorn_p2(float* __restrict__ pq) {
    int col = blockIdx.x * 256 + threadIdx.x;
    float s[8] = {0.f, 0.f, 0.f, 0.f, 0.f, 0.f, 0.f, 0.f};
    for (int c = 0; c < NLCH; ++c) {
        float* base = pq + ((size_t)c * BDI + col) * 16;
        float P[8], Q[8];
#pragma unroll
        for (int n = 0; n < 8; n += 4) {
            *(float4*)&P[n] = *(const float4*)(base + n);
            *(float4*)&Q[n] = *(const float4*)(base + 8 + n);
        }
#pragma unroll
        for (int n = 0; n < 8; n += 4)
            *(float4*)(base + n) = make_float4(s[n], s[n + 1], s[n + 2], s[n + 3]);
#pragma unroll
        for (int n = 0; n < 8; ++n) s[n] = fmaf(P[n], s[n], Q[n]);
    }
}

__global__ __launch_bounds__(256) void longhorn_p3(bf16* __restrict__ xb_y,
                                                   const bf16* __restrict__ z,
                                                   const float* __restrict__ xdbl,
                                                   const float* __restrict__ dtw,
                                                   const float* __restrict__ dtb_v,
                                                   const float* __restrict__ Dv,
                                                   const float* __restrict__ pq) {
    int idx = blockIdx.x * 256 + threadIdx.x;
    int ch = idx / BDI;
    int col = idx % BDI;
    int b = col / DI, d = col % DI;
    float w32[32];
#pragma unroll
    for (int i = 0; i < 32; ++i) w32[i] = dtw[d * 32 + i];
    float dtb = dtb_v[d], Dd = Dv[d];
    float s[8];
    {
        const float* base = pq + (size_t)idx * 16;
#pragma unroll
        for (int n = 0; n < 8; n += 4) *(float4*)&s[n] = *(const float4*)(base + n);
    }
    size_t rbase = ((size_t)b * L_SEQ + ch * LCH) * DI + d;
    const float* xdb = xdbl + ((size_t)b * L_SEQ + ch * LCH) * 48;

    float xv = b2f(xb_y[rbase]);
    float zv = b2f(z[rbase]);
    for (int t = 0; t < LCH; ++t) {
        float x_c = xv, z_c = zv;
        if (t + 1 < LCH) {
            size_t nidx = rbase + (size_t)(t + 1) * DI;
            xv = b2f(xb_y[nidx]);
            zv = b2f(z[nidx]);
        }
        const float* row = xdb + (size_t)t * 48;
        float dt_c = 0.f;
#pragma unroll
        for (int i = 0; i < 32; i += 4) {
            float4 r4 = *(const float4*)(row + i);
            dt_c = fmaf(r4.x, w32[i + 0], dt_c);
            dt_c = fmaf(r4.y, w32[i + 1], dt_c);
            dt_c = fmaf(r4.z, w32[i + 2], dt_c);
            dt_c = fmaf(r4.w, w32[i + 3], dt_c);
        }
        float kq[16];
#pragma unroll
        for (int i = 0; i < 16; i += 4) *(float4*)&kq[i] = *(const float4*)(row + 32 + i);
        float sig = sigmoidf_(dt_c + dtb);
        float ksq = 0.f;
#pragma unroll
        for (int n = 0; n < 8; ++n) ksq = fmaf(kq[n], kq[n], ksq);
        float dts = sig / (1.f + sig * ksq);
        float y = 0.f;
#pragma unroll
        for (int n = 0; n < 8; ++n) {
            float dB = dts * kq[n];
            s[n] = s[n] * (1.f - dB * kq[n]) + x_c * dB;
            y = fmaf(s[n], kq[8 + n], y);
        }
        y = fmaf(Dd, x_c, y);
        float out = y * (z_c * sigmoidf_(z_c));
        xb_y[rbase + (size_t)t * DI] = f2b(out);
    }
}

// ---------------------------------------------------------------- fused TTT prep + 16x16 Gram (xkf removed; gram/eta/q0 only)
__global__ __launch_bounds__(128) void prep_gram_k(const bf16* __restrict__ proj,
                                                   const float* __restrict__ lr_bias,
                                                   const float* __restrict__ tok_idx,
                                                   const float* __restrict__ tok_bias,
                                                   const float* __restrict__ ln_w,
                                                   const float* __restrict__ ln_b,
                                                   float* __restrict__ etav,
                                                   float* __restrict__ q0s,
                                                   float* __restrict__ gram) {
    __shared__ __align__(16) float xs[128][68];
    int bh = blockIdx.x >> 4;
    int blk16 = blockIdx.x & 15;
    int tid = threadIdx.x;
    int t = blk16 * 128 + tid;
    int b = bh >> 3, h = bh & 7;
    const bf16* prow = proj + ((size_t)b * L_SEQ + t) * PROJW;
    const bf16* pk = prow + h * 64;
    const bf16* pv = prow + 512 + h * 64;
    const float* lwp = ln_w + h * 64;
    const float* lbp = ln_b + h * 64;
    float q0 = 0.f;
#pragma unroll
    for (int i = 0; i < 64; i += 8) {
        short8v sk = *(const short8v*)(pk + i);
        short8v sv = *(const short8v*)(pv + i);
        float v[8];
#pragma unroll
        for (int j = 0; j < 8; ++j) {
            float xk = us2f((unsigned short)sk[j]);
            float xv = us2f((unsigned short)sv[j]);
            v[j] = xk;
            q0 = fmaf((lbp[i + j] - xv + xk), lwp[i + j], q0);
        }
        *(float4*)&xs[tid][i]     = make_float4(v[0], v[1], v[2], v[3]);
        *(float4*)&xs[tid][i + 4] = make_float4(v[4], v[5], v[6], v[7]);
    }
    float eta = sigmoidf_(b2f(prow[1536 + h]) + lr_bias[h]) *
                fmaxf(tok_idx[t] + tok_bias[t], 0.f);
    size_t o = (size_t)bh * L_SEQ + t;
    etav[o] = eta;
    q0s[o]  = q0;
    __syncthreads();
    int chunk = tid >> 4, tt = tid & 15;
    const float* rt = &xs[chunk * 16 + tt][0];
    float* dst = gram + (((size_t)bh * 128 + blk16 * 8 + chunk) * 16 + tt) * 16;
#pragma unroll
    for (int ss = 0; ss < 16; ++ss) {
        const float* rs = &xs[chunk * 16 + ss][0];
        float a0 = 0.f, a1 = 0.f, a2 = 0.f, a3 = 0.f;
#pragma unroll
        for (int j = 0; j < 16; ++j) {
            float4 u = *(const float4*)(rt + 4 * j);
            float4 v = *(const float4*)(rs + 4 * j);
            a0 = fmaf(u.x, v.x, a0); a1 = fmaf(u.y, v.y, a1);
            a2 = fmaf(u.z, v.z, a2); a3 = fmaf(u.w, v.w, a3);
        }
        dst[ss] = (a0 + a1) + (a2 + a3);
    }
}

// ---------------------------------------------------------------- TTT scan body v14: 8 chains/block (2 waves/SIMD TLP)
// Each wave owns one bh-chain + its own LDS slice; no barriers (per-wave vmcnt).
// xk staged as bf16 direct from proj (lossless: xkf held exact bf16 values).
__device__ __forceinline__ void ttt_body(const bf16* __restrict__ proj,
                                         const float* __restrict__ etav,
                                         const float* __restrict__ q0s,
                                         const float* __restrict__ gram16,
                                         const float* __restrict__ W1,
                                         const float* __restrict__ b1,
                                         const float* __restrict__ ln_w,
                                         const float* __restrict__ ln_b,
                                         bf16* __restrict__ xqw) {
    const int tid  = threadIdx.x;
    const int wave = tid >> 6;          // 0..7, chain within block
    const int lane = tid & 63;
    const int bh = blockIdx.x * 8 + wave;
    const int b = bh >> 3, h = bh & 7;

    // per-chain LDS slices (8 chains): total 123,392 B
    __shared__ __align__(16) bf16  xkb[8][2][CHT][64];   // 32 KB
    __shared__ __align__(16) bf16  xvb[8][2][CHT][64];   // 32 KB
    __shared__ __align__(16) float kb[8][2][CHT][CHT];   // 16 KB
    __shared__ __align__(16) float sc[8][2][2][64];      //  8 KB
    __shared__ __align__(16) float z1qb[8][CHT][64];     // 32 KB
    __shared__ float mub[8][CHT];                        // 512 B

    float W[64];
#pragma unroll
    for (int f = 0; f < 64; ++f) W[f] = W1[(size_t)(h * 64 + f) * 64 + lane];
    float bvec = b1[h * 64 + lane];
    float lw = ln_w[h * 64 + lane];
    float lb = ln_b[h * 64 + lane];
    float p = lw * lw;

    const bf16*  pkg = proj + (size_t)b * L_SEQ * PROJW + h * 64;
    const bf16*  pvg = pkg + 512;
    const float* evg = etav + (size_t)bh * L_SEQ;
    const float* qg  = q0s + (size_t)bh * L_SEQ;
    const float* gmg = gram16 + (size_t)bh * 128 * 256;

    float zb[CHT];  // register, static indices only (full unrolls)

    auto stage_async = [&](int c, int bi) {
        const int t0g = c * CHT;
#pragma unroll
        for (int i = 0; i < 2; ++i) {
            const bf16* gpk = pkg + (size_t)(t0g + 8 * i + (lane >> 3)) * PROJW + (lane & 7) * 8;
            __builtin_amdgcn_global_load_lds(
                (const __attribute__((address_space(1))) void*)gpk,
                (__attribute__((address_space(3))) void*)&xkb[wave][bi][8 * i][0], 16, 0, 0);
            const bf16* gpv = pvg + (size_t)(t0g + 8 * i + (lane >> 3)) * PROJW + (lane & 7) * 8;
            __builtin_amdgcn_global_load_lds(
                (const __attribute__((address_space(1))) void*)gpv,
                (__attribute__((address_space(3))) void*)&xvb[wave][bi][8 * i][0], 16, 0, 0);
        }
        {
            const float* gp = gmg + (size_t)c * 256 + lane * 4;
            __builtin_amdgcn_global_load_lds(
                (const __attribute__((address_space(1))) void*)gp,
                (__attribute__((address_space(3))) void*)&kb[wave][bi][0][0], 16, 0, 0);
        }
        __builtin_amdgcn_global_load_lds(
            (const __attribute__((address_space(1))) void*)(evg + t0g + lane),
            (__attribute__((address_space(3))) void*)&sc[wave][bi][0][0], 4, 0, 0);
        __builtin_amdgcn_global_load_lds(
            (const __attribute__((address_space(1))) void*)(qg + t0g + lane),
            (__attribute__((address_space(3))) void*)&sc[wave][bi][1][0], 4, 0, 0);
    };
    auto matvec16 = [&](int nbuf) {
#pragma unroll
        for (int t = 0; t < CHT; ++t) {
            const short8v* row = (const short8v*)&xkb[wave][nbuf][t][0];
            float a0 = 0.f, a1 = 0.f, a2 = 0.f, a3 = 0.f;
#pragma unroll
            for (int j = 0; j < 8; ++j) {
                short8v kv = row[j];
                a0 = fmaf(us2f((unsigned short)kv[0]), W[8 * j + 0], a0);
                a1 = fmaf(us2f((unsigned short)kv[1]), W[8 * j + 1], a1);
                a2 = fmaf(us2f((unsigned short)kv[2]), W[8 * j + 2], a2);
                a3 = fmaf(us2f((unsigned short)kv[3]), W[8 * j + 3], a3);
                a0 = fmaf(us2f((unsigned short)kv[4]), W[8 * j + 4], a0);
                a1 = fmaf(us2f((unsigned short)kv[5]), W[8 * j + 5], a1);
                a2 = fmaf(us2f((unsigned short)kv[6]), W[8 * j + 6], a2);
                a3 = fmaf(us2f((unsigned short)kv[7]), W[8 * j + 7], a3);
            }
            float z = (a0 + a1) + (a2 + a3) + bvec;
            zb[t] = z;
            float m = wave_sum_u(z) * 0.015625f;
            if (lane == 0) mub[wave][t] = m;
        }
    };

    stage_async(0, 0);
    asm volatile("s_waitcnt vmcnt(0)" ::: "memory");
    __builtin_amdgcn_sched_barrier(0);
    matvec16(0);

    bf16* xq = xqw + ((size_t)b * L_SEQ) * DM + h * 64 + lane;

    for (int c = 0; c < NST; ++c) {
        const int cur = c & 1;
        if (c + 1 < NST) stage_async(c + 1, 1 - cur);
        float eg[CHT];
        float bacc = 0.f;
        float4 krA, krB, krC, krD;
        {
            const float4* krow = (const float4*)&kb[wave][cur][0][0];
            krA = krow[0]; krB = krow[1]; krC = krow[2]; krD = krow[3];
        }
        float xk_n = b2f(xkb[wave][cur][0][lane]);
        float xv_n = b2f(xvb[wave][cur][0][lane]);
        float et_n = sc[wave][cur][0][0];
        float q0_n = sc[wave][cur][1][0];
        float mu_n = mub[wave][0];
#pragma unroll
        for (int t = 0; t < CHT; ++t) {
            float kr[CHT];
            *(float4*)&kr[0]  = krA;
            *(float4*)&kr[4]  = krB;
            *(float4*)&kr[8]  = krC;
            *(float4*)&kr[12] = krD;
            float xk_c = xk_n;
            float xv_c = xv_n;
            float eta  = et_n;
            float q0u  = q0_n;
            float muv  = mu_n;
            float zb_v = zb[t];
            if (t + 1 < CHT) {
                const float4* krow = (const float4*)&kb[wave][cur][t + 1][0];
                krA = krow[0]; krB = krow[1]; krC = krow[2]; krD = krow[3];
                xk_n = b2f(xkb[wave][cur][t + 1][lane]);
                xv_n = b2f(xvb[wave][cur][t + 1][lane]);
                et_n = sc[wave][cur][0][t + 1];
                q0_n = sc[wave][cur][1][t + 1];
                mu_n = mub[wave][t + 1];
            }

            float gg0 = bacc, gg1 = 0.f, gg2 = 0.f, gg3 = 0.f;
#pragma unroll
            for (int s = 0; s < t; ++s) {
                if ((s & 3) == 0) gg0 = fmaf(kr[s], eg[s], gg0);
                else if ((s & 3) == 1) gg1 = fmaf(kr[s], eg[s], gg1);
                else if ((s & 3) == 2) gg2 = fmaf(kr[s], eg[s], gg2);
                else gg3 = fmaf(kr[s], eg[s], gg3);
            }
            float z1 = zb_v - ((gg0 + gg1) + (gg2 + gg3));
            float d = z1 - muv;
            float q = (lb - xv_c + xk_c) * lw;
            float S2  = wave_sum_u(d * d);
            float PZ1 = wave_sum_u(p * d);
            float PZ2 = wave_sum_u(p * d * d);
            float Q1  = wave_sum_u(q * d);
            float istd = rsqrtf(S2 * 0.015625f + 1e-6f);
            float A_ = fmaf(istd, PZ1, q0u);
            float Bv = fmaf(istd * istd, PZ2, istd * Q1);
            float xh = d * istd;
            float gxh = fmaf(p, xh, q);
            float grad = (64.f * gxh - A_ - xh * Bv) * (istd * 0.015625f);
            float egt = eta * grad;
            eg[t] = egt;
            bacc += egt;
            z1qb[wave][t][lane] = fmaf(-eta * (kr[t] + 1.f), grad, z1);
        }
        // output pass (v12 structure: off the serial chain, keeps VGPR down)
#pragma unroll 4
        for (int t = 0; t < CHT; ++t) {
            float dq = z1qb[wave][t][lane] - mub[wave][t];
            float SQ = wave_sum_u(dq * dq);
            float istd2 = rsqrtf(SQ * 0.015625f + 1e-6f);
            float xk_c = b2f(xkb[wave][cur][t][lane]);
            float outv = fmaf(lw, dq * istd2, xk_c + lb);
            xq[(size_t)(c * CHT + t) * DM] = f2b(outv);
        }
        if (c + 1 < NST) {
            // W update from eg registers (full unroll -> static indices)
#pragma unroll
            for (int s = 0; s < CHT; ++s) {
                float egs = eg[s];
                const short8v* row = (const short8v*)&xkb[wave][cur][s][0];
#pragma unroll
                for (int j = 0; j < 8; ++j) {
                    short8v kv = row[j];
                    W[8 * j + 0] = fmaf(-egs, us2f((unsigned short)kv[0]), W[8 * j + 0]);
                    W[8 * j + 1] = fmaf(-egs, us2f((unsigned short)kv[1]), W[8 * j + 1]);
                    W[8 * j + 2] = fmaf(-egs, us2f((unsigned short)kv[2]), W[8 * j + 2]);
                    W[8 * j + 3] = fmaf(-egs, us2f((unsigned short)kv[3]), W[8 * j + 3]);
                    W[8 * j + 4] = fmaf(-egs, us2f((unsigned short)kv[4]), W[8 * j + 4]);
                    W[8 * j + 5] = fmaf(-egs, us2f((unsigned short)kv[5]), W[8 * j + 5]);
                    W[8 * j + 6] = fmaf(-egs, us2f((unsigned short)kv[6]), W[8 * j + 6]);
                    W[8 * j + 7] = fmaf(-egs, us2f((unsigned short)kv[7]), W[8 * j + 7]);
                }
            }
            bvec -= bacc;
            asm volatile("s_waitcnt vmcnt(0)" ::: "memory");
            __builtin_amdgcn_sched_barrier(0);
            matvec16(1 - cur);
        }
    }
}

// ---------------------------------------------------------------- hetero: blocks 0-3 ttt (8 chains each), blocks 4+ zlg GEMM
__global__ __launch_bounds__(512) void hetero_k(const bf16* __restrict__ proj,
                                                const float* __restrict__ etav,
                                                const float* __restrict__ q0s,
                                                const float* __restrict__ gram16,
                                                const float* __restrict__ W1,
                                                const float* __restrict__ b1,
                                                const float* __restrict__ ln_w,
                                                const float* __restrict__ ln_b,
                                                bf16* __restrict__ xqw,
                                                const bf16* __restrict__ hred,
                                                const bf16* __restrict__ wcat,
                                                bf16* __restrict__ zl,
                                                bf16* __restrict__ gq,
                                                bf16* __restrict__ gk) {
    if (blockIdx.x < 4) {
        ttt_body(proj, etav, q0s, gram16, W1, b1, ln_w, ln_b, xqw);
        return;
    }
    // -------- GEMM: 256 active threads; barriers executed by all 512
    __shared__ __align__(16) bf16 As[128 * 48];
    __shared__ __align__(16) bf16 Ws[128 * 48];
    const int tid = threadIdx.x;
    const bool act = tid < 256;
    const int bidx = blockIdx.x - 4;
    const int lane = tid & 63;
    const int widx = (tid >> 6) & 3;
    const int bm = (bidx & 63) * 128;
    const int bn = (bidx >> 6) * 128;
    const int wr = (widx >> 1) * 64;
    const int wc = (widx & 1) * 64;

    f32x4 acc[4][4];
#pragma unroll
    for (int i = 0; i < 4; ++i)
#pragma unroll
        for (int j = 0; j < 4; ++j) acc[i][j] = (f32x4){0.f, 0.f, 0.f, 0.f};

    const int r0 = (tid & 255) >> 2;
    const int c0 = tid & 3;
    const int frow = lane & 15;
    const int fk = (lane >> 4) * 8;

    const bf16* pa0 = hred + (size_t)(bm + r0) * DM + c0 * 8;
    const bf16* pa1 = hred + (size_t)(bm + r0 + 64) * DM + c0 * 8;
    const bf16* pb0 = wcat + (size_t)(bn + r0) * DM + c0 * 8;
    const bf16* pb1 = wcat + (size_t)(bn + r0 + 64) * DM + c0 * 8;

    for (int k0 = 0; k0 < DM; k0 += 32) {
        short8v a0, a1, b0, b1;
        if (act) {
            a0 = *(const short8v*)(pa0 + k0);
            a1 = *(const short8v*)(pa1 + k0);
            b0 = *(const short8v*)(pb0 + k0);
            b1 = *(const short8v*)(pb1 + k0);
        }
        __syncthreads();
        if (act) {
            *(short8v*)&As[r0 * 48 + c0 * 8] = a0;
            *(short8v*)&As[(r0 + 64) * 48 + c0 * 8] = a1;
            *(short8v*)&Ws[r0 * 48 + c0 * 8] = b0;
            *(short8v*)&Ws[(r0 + 64) * 48 + c0 * 8] = b1;
        }
        __syncthreads();
        if (act) {
            short8v af[4], bg[4];
#pragma unroll
            for (int mi = 0; mi < 4; ++mi)
                af[mi] = *(const short8v*)&As[(wr + mi * 16 + frow) * 48 + fk];
#pragma unroll
            for (int ni = 0; ni < 4; ++ni)
                bg[ni] = *(const short8v*)&Ws[(wc + ni * 16 + frow) * 48 + fk];
#pragma unroll
            for (int mi = 0; mi < 4; ++mi)
#pragma unroll
                for (int ni = 0; ni < 4; ++ni)
                    acc[mi][ni] = __builtin_amdgcn_mfma_f32_16x16x32_bf16(
                        af[mi], bg[ni], acc[mi][ni], 0, 0, 0);
        }
    }

    if (act) {
#pragma unroll
        for (int ni = 0; ni < 4; ++ni) {
            int col = bn + wc + ni * 16 + (lane & 15);
            int buf = col >> 9;
            int lc = col & 511;
            bf16* Cb = (buf == 0) ? zl : (buf == 1) ? gq : gk;
#pragma unroll
            for (int mi = 0; mi < 4; ++mi) {
                int rbase = bm + wr + mi * 16 + (lane >> 4) * 4;
#pragma unroll
                for (int r = 0; r < 4; ++r)
                    Cb[(size_t)(rbase + r) * 512 + lc] = f2b(acc[mi][ni][r]);
            }
        }
    }
}

// ---------------------------------------------------------------- post-norm + gelu gate
__global__ __launch_bounds__(256) void gated_k(const bf16* __restrict__ xqw,
                                               const bf16* __restrict__ proj,
                                               const float* __restrict__ pnw,
                                               const float* __restrict__ pnb,
                                               bf16* __restrict__ gated) {
    int r = blockIdx.x, tid = threadIdx.x;
    const bf16* row = xqw + (size_t)r * DM;
    float v0 = b2f(row[tid]), v1 = b2f(row[tid + 256]);
    float s = v0 + v1, q = v0 * v0 + v1 * v1;
#pragma unroll
    for (int off = 32; off; off >>= 1) {
        s += __shfl_xor(s, off);
        q += __shfl_xor(q, off);
    }
    __shared__ float sm[8];
    if ((tid & 63) == 0) { sm[tid >> 6] = s; sm[4 + (tid >> 6)] = q; }
    __syncthreads();
    s = sm[0] + sm[1] + sm[2] + sm[3];
    q = sm[4] + sm[5] + sm[6] + sm[7];
    float mu = s * (1.f / 512.f);
    float var = q * (1.f / 512.f) - mu * mu;
    float istd = rsqrtf(var + 1e-5f);
    const bf16* grow = proj + (size_t)r * PROJW + 1024;
    bf16* orow = gated + (size_t)r * DM;
#pragma unroll
    for (int e = 0; e < 2; ++e) {
        int c = tid + e * 256;
        float xv = (e == 0) ? v0 : v1;
        float nv = (xv - mu) * istd * pnw[c] + pnb[c];
        float g = b2f(grow[c]);
        float gg = 0.5f * g * (1.f + tanhf(0.7978845608028654f * (g + 0.044715f * g * g * g)));
        orow[c] = f2b(gg * nv);
    }
}

// ---------------------------------------------------------------- gq mean (bf16 input), two-phase
__global__ __launch_bounds__(256) void mean1_k(const bf16* __restrict__ gq,
                                               float* __restrict__ partial) {
    int blk = blockIdx.x;
    int b = blk >> 4, c = blk & 15;
    int tid = threadIdx.x;
    const bf16* p = gq + ((size_t)b * L_SEQ + c * 128) * DM + tid * 2;
    float a0 = 0.f, a1 = 0.f;
    for (int l = 0; l < 128; ++l) {
        ushort2 u = *(const ushort2*)(p + (size_t)l * DM);
        a0 += us2f(u.x); a1 += us2f(u.y);
    }
    partial[(size_t)blk * DM + tid * 2]     = a0;
    partial[(size_t)blk * DM + tid * 2 + 1] = a1;
}
__global__ __launch_bounds__(256) void mean2_k(const float* __restrict__ partial,
                                               float* __restrict__ gqm) {
    int t = blockIdx.x * 256 + threadIdx.x;
    if (t >= 2048) return;
    int b = t >> 9, d = t & 511;
    float acc = 0.f;
#pragma unroll
    for (int c = 0; c < 16; ++c) acc += partial[(size_t)(b * 16 + c) * DM + d];
    gqm[t] = acc * (1.f / 2048.f);
}

// ---------------------------------------------------------------- gain + final mix (bf16 z inputs)
__global__ __launch_bounds__(64) void final_k(const bf16* __restrict__ zl,
                                              const bf16* __restrict__ zt,
                                              const bf16* __restrict__ gk,
                                              const float* __restrict__ gqm,
                                              const float* __restrict__ alpha,
                                              const float* __restrict__ beta,
                                              float* __restrict__ out,
                                              float* __restrict__ gain_out) {
    int r = blockIdx.x;
    int lane = threadIdx.x;
    int b = r >> 11;
    const bf16* gkr = gk + (size_t)r * DM;
    const float* gmb = gqm + b * DM;
    float acc = 0.f;
#pragma unroll
    for (int i = 0; i < 8; ++i) acc = fmaf(gmb[lane + 64 * i], b2f(gkr[lane + 64 * i]), acc);
#pragma unroll
    for (int off = 32; off; off >>= 1) acc += __shfl_xor(acc, off);
    float score = acc * 0.04419417382415922f;
    float g = sigmoidf_(alpha[0] * score + beta[0]);
    g = fminf(g, 0.55f);
    if (lane == 0) gain_out[r] = g;
    const bf16* zlr = zl + (size_t)r * DM;
    const bf16* ztr = zt + (size_t)r * DM;
    float* orow = out + (size_t)r * DM;
#pragma unroll
    for (int i = 0; i < 8; ++i) {
        int c = lane + 64 * i;
        float a = b2f(zlr[c]);
        orow[c] = a + g * (b2f(ztr[c]) - a);
    }
}

// ---------------------------------------------------------------- host launcher

extern "C" void kernel_launch(void* const* d_in, const int* in_sizes, int n_in,
                              void* d_out, int out_size, void* d_ws, size_t ws_size,
                              hipStream_t stream) {
    const float* x           = (const float*)d_in[0];
    const float* norm_w      = (const float*)d_in[1];
    const float* in_proj_w   = (const float*)d_in[2];
    const float* conv_w      = (const float*)d_in[3];
    const float* conv_b      = (const float*)d_in[4];
    const float* x_proj_w    = (const float*)d_in[5];
    const float* dt_head_w   = (const float*)d_in[6];
    const float* dt_head_b   = (const float*)d_in[7];
    const float* Dvec        = (const float*)d_in[8];
    const float* reduce_w    = (const float*)d_in[9];
    const float* q_net_w     = (const float*)d_in[10];
    const float* gain_q_w    = (const float*)d_in[11];
    const float* gain_k_w    = (const float*)d_in[12];
    const float* alpha       = (const float*)d_in[13];
    const float* beta        = (const float*)d_in[14];
    const float* qkv_w       = (const float*)d_in[15];
    const float* qkv_b       = (const float*)d_in[16];
    const float* ttt_lr_bias = (const float*)d_in[17];
    const float* W1          = (const float*)d_in[18];
    const float* b1          = (const float*)d_in[19];
    const float* token_idx   = (const float*)d_in[20];
    const float* token_bias  = (const float*)d_in[21];
    const float* ttt_ln_w    = (const float*)d_in[22];
    const float* ttt_ln_b    = (const float*)d_in[23];
    const float* post_norm_w = (const float*)d_in[24];
    const float* post_norm_b = (const float*)d_in[25];
    const float* wo_w        = (const float*)d_in[26];
    const float* wo_b        = (const float*)d_in[27];

    const size_t SZ_ROWDM = (size_t)NROWS * DM;
    const size_t MB = 1024u * 1024u;
    const size_t KB = 1024u;
    char* base = (char*)d_ws;

    float* out_p  = (float*)d_out;
    float* res_p  = out_p + SZ_ROWDM;
    float* gain_p = out_p + 2 * SZ_ROWDM;

    if (ws_size < 116 * MB) {
        copy4_k<<<(int)(SZ_ROWDM / 4 / 256), 256, 0, stream>>>(
            (const float4*)x, (float4*)res_p, (int)(SZ_ROWDM / 4));
        return;
    }

    // ---- workspace layout; lifetimes as validated R20 (xkf removed)
    bf16*  inpb   = (bf16*)base;                    // in_proj bf16 [0,6)
    bf16*  xpb    = (bf16*)(base + 6 * MB);         // [6,6.6)
    float* lpq    = (float*)base;                   // [0,12.58)
    bf16*  redb   = (bf16*)base;                    // [0,3)
    bf16*  qkvb   = (bf16*)(base + 3 * MB);         // [3,4.51)
    bf16*  wob16  = (bf16*)(base + 4 * MB + 768 * KB);
    bf16*  wcat   = (bf16*)(base + 114 * MB + 512 * KB);
    bf16*  xn     = (bf16*)(base + 7 * MB);
    bf16*  h_red  = xn;
    bf16*  cside  = (bf16*)(base + 7 * MB);
    bf16*  bufX   = (bf16*)(base + 16 * MB);
    bf16*  bufZ   = (bf16*)(base + 64 * MB);
    float* xdbl   = (float*)(base + 112 * MB);
    float* gqm    = (float*)(base + 113 * MB + 512 * KB);
    float* mpart  = (float*)(base + 114 * MB);
    bf16*  proj   = bufX;
    bf16*  xqw    = bufZ;
    bf16*  zl     = (bf16*)(base + 72 * MB);
    bf16*  gq     = (bf16*)(base + 80 * MB);
    float* gramb  = (float*)(base + 88 * MB);
    bf16*  gk     = (bf16*)(base + 92 * MB);
    bf16*  zttt   = (bf16*)(base + 100 * MB);
    bf16*  gated  = (bf16*)(base + 104 * MB);
    bf16*  chid   = (bf16*)(base + 42 * MB);        // over dead bufX tail
    float* etav   = (float*)(base + 58 * MB);
    float* q0s    = (float*)(base + 58 * MB + 512 * KB);

    // 1. rmsnorm + residual
    rmsnorm_res_k<<<NROWS, 256, 0, stream>>>(x, norm_w, xn, res_p);

    // 2. in_proj cvt + merged GEMM (N=6144 -> bufX|bufZ)
    cvt_k<<<(2 * DI * DM / 4 + 255) / 256, 256, 0, stream>>>(in_proj_w, inpb, 2 * DI * DM / 4);
    {
        dim3 g(NROWS / 128, 2 * DI / 128);
        gemm_inproj<<<g, 256, 0, stream>>>(xn, inpb, bufX, bufZ);
    }

    // 3. wcat cvt
    cvt3_k<<<(3 * 65536 + 255) / 256, 256, 0, stream>>>(q_net_w, gain_q_w, gain_k_w, wcat);

    // 4. conv
    conv_boundary_k<<<((L_SEQ / CTILE - 1) * 2 * BDI) / 256, 256, 0, stream>>>(bufX, cside);
    conv_tile_k<<<((L_SEQ / CTILE) * BDI) / 256, 256, 0, stream>>>(bufX, cside, conv_w, conv_b);

    // 5. x_proj cvt + gemm
    cvt_k<<<(48 * DI / 4 + 255) / 256, 256, 0, stream>>>(x_proj_w, xpb, 48 * DI / 4);
    {
        dim3 g(NROWS / 128, 1);
        gemm_mfma<0, float><<<g, 256, 0, stream>>>(bufX, DI, xpb, DI, nullptr, xdbl, 48, 48, DI);
    }

    // 6. longhorn chunked scan (lpq over dead in_proj/xpb scratch)
    longhorn_p1<<<(NLCH * BDI) / 256, 256, 0, stream>>>(bufX, xdbl, dt_head_w, dt_head_b, lpq);
    longhorn_p2<<<BDI / 256, 256, 0, stream>>>(lpq);
    longhorn_p3<<<(NLCH * BDI) / 256, 256, 0, stream>>>(bufX, bufZ, xdbl, dt_head_w,
                                                        dt_head_b, Dvec, lpq);

    // 7. reduce/qkv/wo cvt (over dead lpq)
    cvt_rqw_k<<<(C_RED + C_QKV + C_WO + 255) / 256, 256, 0, stream>>>(
        reduce_w, qkv_w, wo_w, redb, qkvb, wob16);

    // 8. reduce -> h_red
    {
        dim3 g(NROWS / 128, DM / 128);
        gemm_mfma<0, bf16><<<g, 256, 0, stream>>>(bufX, DI, redb, DI, nullptr, h_red, DM, DM, DI);
    }

    // 9. qkv -> proj
    {
        dim3 g(NROWS / 128, (PROJW + 127) / 128);
        gemm_mfma<1, bf16><<<g, 256, 0, stream>>>(h_red, DM, qkvb, DM, qkv_b, proj, PROJW, PROJW, DM);
    }

    // 10. fused prep+gram (eta/q0/gram only; xk read direct from proj in ttt)
    prep_gram_k<<<32 * 16, 128, 0, stream>>>(proj, ttt_lr_bias, token_idx, token_bias,
                                             ttt_ln_w, ttt_ln_b, etav, q0s, gramb);

    // 11. hetero: ttt (4 blocks x 8 chains, 512 thr) + zl/gq/gk GEMM overlapped
    hetero_k<<<4 + 768, 512, 0, stream>>>(proj, etav, q0s, gramb, W1, b1,
                                          ttt_ln_w, ttt_ln_b, xqw,
                                          h_red, wcat, zl, gq, gk);

    // 12. gated
    gated_k<<<NROWS, 256, 0, stream>>>(xqw, proj, post_norm_w, post_norm_b, gated);

    // 13. wo -> chid ; zttt = chid @ q_net (wcat rows 0-511)
    {
        dim3 g(NROWS / 128, DM / 128);
        gemm_mfma<1, bf16><<<g, 256, 0, stream>>>(gated, DM, wob16, DM, wo_b, chid, DM, DM, DM);
        gemm_mfma<0, bf16><<<g, 256, 0, stream>>>(chid, DM, wcat, DM, nullptr, zttt, DM, DM, DM);
    }

    // 14. gq mean + final
    mean1_k<<<64, 256, 0, stream>>>(gq, mpart);
    mean2_k<<<8, 256, 0, stream>>>(mpart, gqm);
    final_k<<<NROWS, 64, 0, stream>>>(zl, zttt, gk, gqm, alpha, beta, out_p, gain_p);
}

// Round 23
// 2294.909 us; speedup vs baseline: 2.0249x; 1.4858x over previous
//
#include <hip/hip_runtime.h>
#include <hip/hip_bf16.h>
#include <cstdint>
#include <cstddef>

#define L_SEQ 2048
#define BATCH 4
#define DM    512
#define DI    3072
#define NROWS (BATCH * L_SEQ)   // 8192
#define PROJW 1544              // 3*512 + 8
#define CTILE 16
#define BDI   (BATCH * DI)      // 12288
#define SB    64                // ttt staging superblock (tokens)
#define NSB   (L_SEQ / SB)      // 32
#define CHT   16                // ttt serial sub-chunk
#define LCH   128               // longhorn chunk tokens (R17-proven)
#define NLCH  (L_SEQ / LCH)     // 16

using bf16 = __hip_bfloat16;

typedef __attribute__((ext_vector_type(8))) short short8v;
typedef __attribute__((ext_vector_type(4))) float f32x4;

// ---------------------------------------------------------------- utilities

__device__ __forceinline__ float sigmoidf_(float x) { return 1.f / (1.f + __expf(-x)); }
__device__ __forceinline__ float us2f(unsigned int u) {
    union { unsigned int i; float f; } c; c.i = u << 16; return c.f;
}
__device__ __forceinline__ bf16  f2b(float f) { return __float2bfloat16(f); }
__device__ __forceinline__ float b2f(bf16 v)  { return __bfloat162float(v); }
__device__ __forceinline__ void st1(float* p, float v) { *p = v; }
__device__ __forceinline__ void st1(bf16* p, float v)  { *p = f2b(v); }

// DPP-based wave64 sum -> uniform value (validated R4-R20)
template <int CTRL>
__device__ __forceinline__ float dppadd_(float x) {
    int s = __builtin_amdgcn_update_dpp(0, __builtin_bit_cast(int, x), CTRL, 0xF, 0xF, true);
    return x + __builtin_bit_cast(float, s);
}
__device__ __forceinline__ float wave_sum_u(float x) {
    x = dppadd_<0x111>(x);
    x = dppadd_<0x112>(x);
    x = dppadd_<0x114>(x);
    x = dppadd_<0x118>(x);
    x = dppadd_<0x142>(x);
    x = dppadd_<0x143>(x);
    return __builtin_bit_cast(float,
        __builtin_amdgcn_readlane(__builtin_bit_cast(int, x), 63));
}

// ---------------------------------------------------------------- residual copy (ws-too-small fallback only)
__global__ __launch_bounds__(256) void copy4_k(const float4* __restrict__ in,
                                               float4* __restrict__ out, int n) {
    int i = blockIdx.x * 256 + threadIdx.x;
    if (i < n) out[i] = in[i];
}

// ---------------------------------------------------------------- f32 -> bf16 weight convert
__global__ __launch_bounds__(256) void cvt_k(const float* __restrict__ in,
                                             bf16* __restrict__ out, int n4) {
    int i = blockIdx.x * 256 + threadIdx.x;
    if (i >= n4) return;
    float4 v = ((const float4*)in)[i];
    out[4 * i + 0] = f2b(v.x);
    out[4 * i + 1] = f2b(v.y);
    out[4 * i + 2] = f2b(v.z);
    out[4 * i + 3] = f2b(v.w);
}

// concat 3x [512][512] f32 -> bf16 wcat[1536][512]
__global__ __launch_bounds__(256) void cvt3_k(const float* __restrict__ a,
                                              const float* __restrict__ b,
                                              const float* __restrict__ c,
                                              bf16* __restrict__ out) {
    int i = blockIdx.x * 256 + threadIdx.x;
    const int seg = 512 * 512 / 4;
    if (i >= 3 * seg) return;
    const float* src = (i < seg) ? a : (i < 2 * seg) ? b : c;
    int j = (i < seg) ? i : (i < 2 * seg) ? i - seg : i - 2 * seg;
    float4 v = ((const float4*)src)[j];
    bf16* o = out + (size_t)i * 4;
    o[0] = f2b(v.x); o[1] = f2b(v.y); o[2] = f2b(v.z); o[3] = f2b(v.w);
}

// merged cvt: reduce | qkv | wo  (run after longhorn, over dead lpq region)
#define C_RED  393216                  // reduce f4 units
#define C_QKV  197632                  // qkv
#define C_WO   65536                   // wo
__global__ __launch_bounds__(256) void cvt_rqw_k(const float* __restrict__ reduce_w,
                                                 const float* __restrict__ qkv_w,
                                                 const float* __restrict__ wo_w,
                                                 bf16* __restrict__ redb,
                                                 bf16* __restrict__ qkvb,
                                                 bf16* __restrict__ wob) {
    int i = blockIdx.x * 256 + threadIdx.x;
    const float* src;
    bf16* dst;
    int j;
    if (i < C_RED)                     { src = reduce_w; dst = redb; j = i; }
    else if (i < C_RED + C_QKV)        { src = qkv_w;    dst = qkvb; j = i - C_RED; }
    else if (i < C_RED + C_QKV + C_WO) { src = wo_w;     dst = wob;  j = i - C_RED - C_QKV; }
    else return;
    float4 v = ((const float4*)src)[j];
    bf16* o = dst + (size_t)j * 4;
    o[0] = f2b(v.x); o[1] = f2b(v.y); o[2] = f2b(v.z); o[3] = f2b(v.w);
}

// ---------------------------------------------------------------- rmsnorm + residual copy fused
__global__ __launch_bounds__(256) void rmsnorm_res_k(const float* __restrict__ x,
                                                     const float* __restrict__ w,
                                                     bf16* __restrict__ xn,
                                                     float* __restrict__ res) {
    int r = blockIdx.x, tid = threadIdx.x;
    const float* row = x + (size_t)r * DM;
    float v0 = row[tid], v1 = row[tid + 256];
    float q = v0 * v0 + v1 * v1;
#pragma unroll
    for (int off = 32; off; off >>= 1) q += __shfl_xor(q, off);
    __shared__ float sm[4];
    if ((tid & 63) == 0) sm[tid >> 6] = q;
    __syncthreads();
    q = sm[0] + sm[1] + sm[2] + sm[3];
    float scale = rsqrtf(q * (1.f / 512.f) + 1e-5f);
    bf16* orow = xn + (size_t)r * DM;
    float* rrow = res + (size_t)r * DM;
    orow[tid]       = f2b(v0 * scale * w[tid]);
    orow[tid + 256] = f2b(v1 * scale * w[tid + 256]);
    rrow[tid]       = v0;
    rrow[tid + 256] = v1;
}

// ---------------------------------------------------------------- bf16 MFMA GEMM (validated R3)
template <int BIAS, typename TC>
__global__ __launch_bounds__(256) void gemm_mfma(const bf16* __restrict__ A, int lda,
                                                 const bf16* __restrict__ Wb, int ldw,
                                                 const float* __restrict__ bias,
                                                 TC* __restrict__ C, int ldc,
                                                 int N, int K) {
    __shared__ __align__(16) bf16 As[128 * 48];
    __shared__ __align__(16) bf16 Ws[128 * 48];
    const int tid = threadIdx.x;
    const int lane = tid & 63;
    const int widx = tid >> 6;
    const int bm = blockIdx.x * 128;
    const int bn = blockIdx.y * 128;
    const int wr = (widx >> 1) * 64;
    const int wc = (widx & 1) * 64;

    f32x4 acc[4][4];
#pragma unroll
    for (int i = 0; i < 4; ++i)
#pragma unroll
        for (int j = 0; j < 4; ++j) acc[i][j] = (f32x4){0.f, 0.f, 0.f, 0.f};

    const int r0 = tid >> 2;
    const int c0 = tid & 3;
    const int frow = lane & 15;
    const int fk = (lane >> 4) * 8;

    int n0 = bn + r0;       if (n0 > N - 1) n0 = N - 1;
    int n1 = bn + r0 + 64;  if (n1 > N - 1) n1 = N - 1;
    const bf16* pa0 = A + (size_t)(bm + r0) * lda + c0 * 8;
    const bf16* pa1 = A + (size_t)(bm + r0 + 64) * lda + c0 * 8;
    const bf16* pb0 = Wb + (size_t)n0 * ldw + c0 * 8;
    const bf16* pb1 = Wb + (size_t)n1 * ldw + c0 * 8;

    for (int k0 = 0; k0 < K; k0 += 32) {
        short8v a0 = *(const short8v*)(pa0 + k0);
        short8v a1 = *(const short8v*)(pa1 + k0);
        short8v b0 = *(const short8v*)(pb0 + k0);
        short8v b1 = *(const short8v*)(pb1 + k0);
        __syncthreads();
        *(short8v*)&As[r0 * 48 + c0 * 8] = a0;
        *(short8v*)&As[(r0 + 64) * 48 + c0 * 8] = a1;
        *(short8v*)&Ws[r0 * 48 + c0 * 8] = b0;
        *(short8v*)&Ws[(r0 + 64) * 48 + c0 * 8] = b1;
        __syncthreads();
        short8v af[4], bg[4];
#pragma unroll
        for (int mi = 0; mi < 4; ++mi)
            af[mi] = *(const short8v*)&As[(wr + mi * 16 + frow) * 48 + fk];
#pragma unroll
        for (int ni = 0; ni < 4; ++ni)
            bg[ni] = *(const short8v*)&Ws[(wc + ni * 16 + frow) * 48 + fk];
#pragma unroll
        for (int mi = 0; mi < 4; ++mi)
#pragma unroll
            for (int ni = 0; ni < 4; ++ni)
                acc[mi][ni] = __builtin_amdgcn_mfma_f32_16x16x32_bf16(
                    af[mi], bg[ni], acc[mi][ni], 0, 0, 0);
    }

#pragma unroll
    for (int ni = 0; ni < 4; ++ni) {
        int col = bn + wc + ni * 16 + (lane & 15);
        if (col < N) {
            float bz = BIAS ? bias[col] : 0.f;
#pragma unroll
            for (int mi = 0; mi < 4; ++mi) {
                int rbase = bm + wr + mi * 16 + (lane >> 4) * 4;
#pragma unroll
                for (int r = 0; r < 4; ++r) {
                    float v = acc[mi][ni][r] + bz;
                    st1(&C[(size_t)(rbase + r) * ldc + col], v);
                }
            }
        }
    }
}

// ---------------------------------------------------------------- merged in_proj GEMM: N=6144, split C (bufX | bufZ)
__global__ __launch_bounds__(256) void gemm_inproj(const bf16* __restrict__ A,
                                                   const bf16* __restrict__ Wb,
                                                   bf16* __restrict__ cx,
                                                   bf16* __restrict__ cz) {
    __shared__ __align__(16) bf16 As[128 * 48];
    __shared__ __align__(16) bf16 Ws[128 * 48];
    const int tid = threadIdx.x;
    const int lane = tid & 63;
    const int widx = tid >> 6;
    const int bm = blockIdx.x * 128;
    const int bn = blockIdx.y * 128;
    const int wr = (widx >> 1) * 64;
    const int wc = (widx & 1) * 64;

    f32x4 acc[4][4];
#pragma unroll
    for (int i = 0; i < 4; ++i)
#pragma unroll
        for (int j = 0; j < 4; ++j) acc[i][j] = (f32x4){0.f, 0.f, 0.f, 0.f};

    const int r0 = tid >> 2;
    const int c0 = tid & 3;
    const int frow = lane & 15;
    const int fk = (lane >> 4) * 8;

    const bf16* pa0 = A + (size_t)(bm + r0) * DM + c0 * 8;
    const bf16* pa1 = A + (size_t)(bm + r0 + 64) * DM + c0 * 8;
    const bf16* pb0 = Wb + (size_t)(bn + r0) * DM + c0 * 8;
    const bf16* pb1 = Wb + (size_t)(bn + r0 + 64) * DM + c0 * 8;

    for (int k0 = 0; k0 < DM; k0 += 32) {
        short8v a0 = *(const short8v*)(pa0 + k0);
        short8v a1 = *(const short8v*)(pa1 + k0);
        short8v b0 = *(const short8v*)(pb0 + k0);
        short8v b1 = *(const short8v*)(pb1 + k0);
        __syncthreads();
        *(short8v*)&As[r0 * 48 + c0 * 8] = a0;
        *(short8v*)&As[(r0 + 64) * 48 + c0 * 8] = a1;
        *(short8v*)&Ws[r0 * 48 + c0 * 8] = b0;
        *(short8v*)&Ws[(r0 + 64) * 48 + c0 * 8] = b1;
        __syncthreads();
        short8v af[4], bg[4];
#pragma unroll
        for (int mi = 0; mi < 4; ++mi)
            af[mi] = *(const short8v*)&As[(wr + mi * 16 + frow) * 48 + fk];
#pragma unroll
        for (int ni = 0; ni < 4; ++ni)
            bg[ni] = *(const short8v*)&Ws[(wc + ni * 16 + frow) * 48 + fk];
#pragma unroll
        for (int mi = 0; mi < 4; ++mi)
#pragma unroll
            for (int ni = 0; ni < 4; ++ni)
                acc[mi][ni] = __builtin_amdgcn_mfma_f32_16x16x32_bf16(
                    af[mi], bg[ni], acc[mi][ni], 0, 0, 0);
    }

    bf16* Cb = (bn < DI) ? cx : cz;
    const int coff = (bn < DI) ? 0 : DI;
#pragma unroll
    for (int ni = 0; ni < 4; ++ni) {
        int col = bn + wc + ni * 16 + (lane & 15) - coff;
#pragma unroll
        for (int mi = 0; mi < 4; ++mi) {
            int rbase = bm + wr + mi * 16 + (lane >> 4) * 4;
#pragma unroll
            for (int r = 0; r < 4; ++r)
                Cb[(size_t)(rbase + r) * DI + col] = f2b(acc[mi][ni][r]);
        }
    }
}

// ---------------------------------------------------------------- conv: boundary row copy
__global__ __launch_bounds__(256) void conv_boundary_k(const bf16* __restrict__ x,
                                                       bf16* __restrict__ side) {
    int idx = blockIdx.x * 256 + threadIdx.x;
    const int total = (L_SEQ / CTILE - 1) * 2 * BDI;
    if (idx >= total) return;
    int col = idx % BDI;
    int rr = idx / BDI;
    int tile = (rr >> 1) + 1;
    int r = rr & 1;
    int b = col / DI, d = col % DI;
    int l = tile * CTILE - 2 + r;
    side[idx] = x[((size_t)b * L_SEQ + l) * DI + d];
}

// ---------------------------------------------------------------- conv tile: causal depthwise conv3 + silu
__global__ __launch_bounds__(256) void conv_tile_k(bf16* __restrict__ x,
                                                   const bf16* __restrict__ side,
                                                   const float* __restrict__ cw,
                                                   const float* __restrict__ cb) {
    int idx = blockIdx.x * 256 + threadIdx.x;
    const int total = (L_SEQ / CTILE) * BDI;
    if (idx >= total) return;
    int col = idx % BDI;
    int tile = idx / BDI;
    int b = col / DI, d = col % DI;
    float w0 = cw[3 * d], w1 = cw[3 * d + 1], w2 = cw[3 * d + 2], bias = cb[d];
    size_t base = ((size_t)b * L_SEQ + tile * CTILE) * DI + d;
    float xm2, xm1;
    if (tile == 0) { xm2 = 0.f; xm1 = 0.f; }
    else {
        const bf16* sp = side + ((size_t)(tile - 1) * 2) * BDI + col;
        xm2 = b2f(sp[0]);
        xm1 = b2f(sp[BDI]);
    }
    float cur = b2f(x[base]);
#pragma unroll
    for (int i = 0; i < CTILE; ++i) {
        float nxt = (i + 1 < CTILE) ? b2f(x[base + (size_t)(i + 1) * DI]) : 0.f;
        float a = bias + w0 * xm2 + w1 * xm1 + w2 * cur;
        x[base + (size_t)i * DI] = f2b(a * sigmoidf_(a));
        xm2 = xm1; xm1 = cur; cur = nxt;
    }
}

// ---------------------------------------------------------------- longhorn chunked scan (validated R13; LCH=128)
__global__ __launch_bounds__(256) void longhorn_p1(const bf16* __restrict__ xb,
                                                   const float* __restrict__ xdbl,
                                                   const float* __restrict__ dtw,
                                                   const float* __restrict__ dtb_v,
                                                   float* __restrict__ pq) {
    int idx = blockIdx.x * 256 + threadIdx.x;
    int ch = idx / BDI;
    int col = idx % BDI;
    int b = col / DI, d = col % DI;
    float w32[32];
#pragma unroll
    for (int i = 0; i < 32; ++i) w32[i] = dtw[d * 32 + i];
    float dtb = dtb_v[d];
    float P[8] = {1.f, 1.f, 1.f, 1.f, 1.f, 1.f, 1.f, 1.f};
    float Q[8] = {0.f, 0.f, 0.f, 0.f, 0.f, 0.f, 0.f, 0.f};
    size_t rbase = ((size_t)b * L_SEQ + ch * LCH) * DI + d;
    const float* xdb = xdbl + ((size_t)b * L_SEQ + ch * LCH) * 48;

    float xv = b2f(xb[rbase]);
    for (int t = 0; t < LCH; ++t) {
        float x_c = xv;
        if (t + 1 < LCH) xv = b2f(xb[rbase + (size_t)(t + 1) * DI]);
        const float* row = xdb + (size_t)t * 48;
        float dt_c = 0.f;
#pragma unroll
        for (int i = 0; i < 32; i += 4) {
            float4 r4 = *(const float4*)(row + i);
            dt_c = fmaf(r4.x, w32[i + 0], dt_c);
            dt_c = fmaf(r4.y, w32[i + 1], dt_c);
            dt_c = fmaf(r4.z, w32[i + 2], dt_c);
            dt_c = fmaf(r4.w, w32[i + 3], dt_c);
        }
        float kq[8];
#pragma unroll
        for (int i = 0; i < 8; i += 4) *(float4*)&kq[i] = *(const float4*)(row + 32 + i);
        float sig = sigmoidf_(dt_c + dtb);
        float ksq = 0.f;
#pragma unroll
        for (int n = 0; n < 8; ++n) ksq = fmaf(kq[n], kq[n], ksq);
        float dts = sig / (1.f + sig * ksq);
#pragma unroll
        for (int n = 0; n < 8; ++n) {
            float dB = dts * kq[n];
            float a = 1.f - dB * kq[n];
            P[n] *= a;
            Q[n] = fmaf(Q[n], a, x_c * dB);
        }
    }
    float* o = pq + (size_t)idx * 16;
#pragma unroll
    for (int n = 0; n < 8; n += 4) {
        *(float4*)(o + n)     = make_float4(P[n], P[n + 1], P[n + 2], P[n + 3]);
        *(float4*)(o + 8 + n) = make_float4(Q[n], Q[n + 1], Q[n + 2], Q[n + 3]);
    }
}

__global__ __launch_bounds__(256) void longhorn_p2(float* __restrict__ pq) {
    int col = blockIdx.x * 256 + threadIdx.x;
    float s[8] = {0.f, 0.f, 0.f, 0.f, 0.f, 0.f, 0.f, 0.f};
    for (int c = 0; c < NLCH; ++c) {
        float* base = pq + ((size_t)c * BDI + col) * 16;
        float P[8], Q[8];
#pragma unroll
        for (int n = 0; n < 8; n += 4) {
            *(float4*)&P[n] = *(const float4*)(base + n);
            *(float4*)&Q[n] = *(const float4*)(base + 8 + n);
        }
#pragma unroll
        for (int n = 0; n < 8; n += 4)
            *(float4*)(base + n) = make_float4(s[n], s[n + 1], s[n + 2], s[n + 3]);
#pragma unroll
        for (int n = 0; n < 8; ++n) s[n] = fmaf(P[n], s[n], Q[n]);
    }
}

__global__ __launch_bounds__(256) void longhorn_p3(bf16* __restrict__ xb_y,
                                                   const bf16* __restrict__ z,
                                                   const float* __restrict__ xdbl,
                                                   const float* __restrict__ dtw,
                                                   const float* __restrict__ dtb_v,
                                                   const float* __restrict__ Dv,
                                                   const float* __restrict__ pq) {
    int idx = blockIdx.x * 256 + threadIdx.x;
    int ch = idx / BDI;
    int col = idx % BDI;
    int b = col / DI, d = col % DI;
    float w32[32];
#pragma unroll
    for (int i = 0; i < 32; ++i) w32[i] = dtw[d * 32 + i];
    float dtb = dtb_v[d], Dd = Dv[d];
    float s[8];
    {
        const float* base = pq + (size_t)idx * 16;
#pragma unroll
        for (int n = 0; n < 8; n += 4) *(float4*)&s[n] = *(const float4*)(base + n);
    }
    size_t rbase = ((size_t)b * L_SEQ + ch * LCH) * DI + d;
    const float* xdb = xdbl + ((size_t)b * L_SEQ + ch * LCH) * 48;

    float xv = b2f(xb_y[rbase]);
    float zv = b2f(z[rbase]);
    for (int t = 0; t < LCH; ++t) {
        float x_c = xv, z_c = zv;
        if (t + 1 < LCH) {
            size_t nidx = rbase + (size_t)(t + 1) * DI;
            xv = b2f(xb_y[nidx]);
            zv = b2f(z[nidx]);
        }
        const float* row = xdb + (size_t)t * 48;
        float dt_c = 0.f;
#pragma unroll
        for (int i = 0; i < 32; i += 4) {
            float4 r4 = *(const float4*)(row + i);
            dt_c = fmaf(r4.x, w32[i + 0], dt_c);
            dt_c = fmaf(r4.y, w32[i + 1], dt_c);
            dt_c = fmaf(r4.z, w32[i + 2], dt_c);
            dt_c = fmaf(r4.w, w32[i + 3], dt_c);
        }
        float kq[16];
#pragma unroll
        for (int i = 0; i < 16; i += 4) *(float4*)&kq[i] = *(const float4*)(row + 32 + i);
        float sig = sigmoidf_(dt_c + dtb);
        float ksq = 0.f;
#pragma unroll
        for (int n = 0; n < 8; ++n) ksq = fmaf(kq[n], kq[n], ksq);
        float dts = sig / (1.f + sig * ksq);
        float y = 0.f;
#pragma unroll
        for (int n = 0; n < 8; ++n) {
            float dB = dts * kq[n];
            s[n] = s[n] * (1.f - dB * kq[n]) + x_c * dB;
            y = fmaf(s[n], kq[8 + n], y);
        }
        y = fmaf(Dd, x_c, y);
        float out = y * (z_c * sigmoidf_(z_c));
        xb_y[rbase + (size_t)t * DI] = f2b(out);
    }
}

// ---------------------------------------------------------------- fused TTT prep + 16x16 Gram (validated R19/R20)
__global__ __launch_bounds__(128) void prep_gram_k(const bf16* __restrict__ proj,
                                                   const float* __restrict__ lr_bias,
                                                   const float* __restrict__ tok_idx,
                                                   const float* __restrict__ tok_bias,
                                                   const float* __restrict__ ln_w,
                                                   const float* __restrict__ ln_b,
                                                   float* __restrict__ xkf,
                                                   float* __restrict__ etav,
                                                   float* __restrict__ q0s,
                                                   float* __restrict__ gram) {
    __shared__ __align__(16) float xs[128][68];
    int bh = blockIdx.x >> 4;
    int blk16 = blockIdx.x & 15;
    int tid = threadIdx.x;
    int t = blk16 * 128 + tid;
    int b = bh >> 3, h = bh & 7;
    const bf16* prow = proj + ((size_t)b * L_SEQ + t) * PROJW;
    const bf16* pk = prow + h * 64;
    const bf16* pv = prow + 512 + h * 64;
    const float* lwp = ln_w + h * 64;
    const float* lbp = ln_b + h * 64;
    float* xo = xkf + ((size_t)bh * L_SEQ + t) * 64;
    float q0 = 0.f;
#pragma unroll
    for (int i = 0; i < 64; i += 8) {
        short8v sk = *(const short8v*)(pk + i);
        short8v sv = *(const short8v*)(pv + i);
        float v[8];
#pragma unroll
        for (int j = 0; j < 8; ++j) {
            float xk = us2f((unsigned short)sk[j]);
            float xv = us2f((unsigned short)sv[j]);
            v[j] = xk;
            q0 = fmaf((lbp[i + j] - xv + xk), lwp[i + j], q0);
        }
        float4 lo = make_float4(v[0], v[1], v[2], v[3]);
        float4 hi = make_float4(v[4], v[5], v[6], v[7]);
        *(float4*)(xo + i)     = lo;
        *(float4*)(xo + i + 4) = hi;
        *(float4*)&xs[tid][i]     = lo;
        *(float4*)&xs[tid][i + 4] = hi;
    }
    float eta = sigmoidf_(b2f(prow[1536 + h]) + lr_bias[h]) *
                fmaxf(tok_idx[t] + tok_bias[t], 0.f);
    size_t o = (size_t)bh * L_SEQ + t;
    etav[o] = eta;
    q0s[o]  = q0;
    __syncthreads();
    int chunk = tid >> 4, tt = tid & 15;
    const float* rt = &xs[chunk * 16 + tt][0];
    float* dst = gram + (((size_t)bh * 128 + blk16 * 8 + chunk) * 16 + tt) * 16;
#pragma unroll
    for (int ss = 0; ss < 16; ++ss) {
        const float* rs = &xs[chunk * 16 + ss][0];
        float a0 = 0.f, a1 = 0.f, a2 = 0.f, a3 = 0.f;
#pragma unroll
        for (int j = 0; j < 16; ++j) {
            float4 u = *(const float4*)(rt + 4 * j);
            float4 v = *(const float4*)(rs + 4 * j);
            a0 = fmaf(u.x, v.x, a0); a1 = fmaf(u.y, v.y, a1);
            a2 = fmaf(u.z, v.z, a2); a3 = fmaf(u.w, v.w, a3);
        }
        dst[ss] = (a0 + a1) + (a2 + a3);
    }
}

// ---------------------------------------------------------------- TTT scan body (v12, validated R16-R20)
__device__ __forceinline__ void ttt_body(const bf16* __restrict__ proj,
                                         const float* __restrict__ xkf,
                                         const float* __restrict__ etav,
                                         const float* __restrict__ q0s,
                                         const float* __restrict__ gram16,
                                         const float* __restrict__ W1,
                                         const float* __restrict__ b1,
                                         const float* __restrict__ ln_w,
                                         const float* __restrict__ ln_b,
                                         bf16* __restrict__ xqw) {
    const int lane = threadIdx.x;
    const int bh = blockIdx.x;
    const int b = bh >> 3, h = bh & 7;

    __shared__ __align__(16) float xkb[2][SB][64];
    __shared__ __align__(16) bf16  xvb[2][SB][64];
    __shared__ __align__(16) float kb[2][4][CHT][CHT];
    __shared__ __align__(16) float sc[2][2][SB];
    __shared__ __align__(16) float zbb[CHT][64];
    __shared__ __align__(16) float z1qb[CHT][64];
    __shared__ __align__(16) float egb[CHT][64];
    __shared__ float mub[CHT];

    float W[64];
#pragma unroll
    for (int f = 0; f < 64; ++f) W[f] = W1[(size_t)(h * 64 + f) * 64 + lane];
    float bvec = b1[h * 64 + lane];
    float lw = ln_w[h * 64 + lane];
    float lb = ln_b[h * 64 + lane];
    float p = lw * lw;

    const float* kfg = xkf + (size_t)bh * L_SEQ * 64;
    const bf16*  pvg = proj + (size_t)b * L_SEQ * PROJW + 512 + h * 64;
    const float* evg = etav + (size_t)bh * L_SEQ;
    const float* qg  = q0s + (size_t)bh * L_SEQ;
    const float* gmg = gram16 + (size_t)bh * 128 * 256;

    auto stage_async = [&](int c, int bi) {
        const int t0g = c * SB;
#pragma unroll
        for (int i = 0; i < 16; ++i) {
            const float* gp = kfg + (size_t)(t0g + 4 * i) * 64 + lane * 4;
            __builtin_amdgcn_global_load_lds(
                (const __attribute__((address_space(1))) void*)gp,
                (__attribute__((address_space(3))) void*)&xkb[bi][4 * i][0], 16, 0, 0);
        }
#pragma unroll
        for (int i = 0; i < 8; ++i) {
            const bf16* gp = pvg + (size_t)(t0g + 8 * i + (lane >> 3)) * PROJW + (lane & 7) * 8;
            __builtin_amdgcn_global_load_lds(
                (const __attribute__((address_space(1))) void*)gp,
                (__attribute__((address_space(3))) void*)&xvb[bi][8 * i][0], 16, 0, 0);
        }
#pragma unroll
        for (int i = 0; i < 4; ++i) {
            const float* gp = gmg + (size_t)c * 1024 + i * 256 + lane * 4;
            __builtin_amdgcn_global_load_lds(
                (const __attribute__((address_space(1))) void*)gp,
                (__attribute__((address_space(3))) void*)(&kb[bi][0][0][0] + i * 256), 16, 0, 0);
        }
        {
            const float* g0 = evg + t0g + lane;
            __builtin_amdgcn_global_load_lds(
                (const __attribute__((address_space(1))) void*)g0,
                (__attribute__((address_space(3))) void*)&sc[bi][0][0], 4, 0, 0);
            const float* g1 = qg + t0g + lane;
            __builtin_amdgcn_global_load_lds(
                (const __attribute__((address_space(1))) void*)g1,
                (__attribute__((address_space(3))) void*)&sc[bi][1][0], 4, 0, 0);
        }
    };
    auto matvec16 = [&](int nbuf, int nt0) {
#pragma unroll 4
        for (int t = 0; t < CHT; ++t) {
            const float4* row = (const float4*)&xkb[nbuf][nt0 + t][0];
            float a0 = 0.f, a1 = 0.f, a2 = 0.f, a3 = 0.f;
#pragma unroll
            for (int j = 0; j < 16; ++j) {
                float4 kv = row[j];
                a0 = fmaf(kv.x, W[4 * j + 0], a0);
                a1 = fmaf(kv.y, W[4 * j + 1], a1);
                a2 = fmaf(kv.z, W[4 * j + 2], a2);
                a3 = fmaf(kv.w, W[4 * j + 3], a3);
            }
            float zb = (a0 + a1) + (a2 + a3) + bvec;
            zbb[t][lane] = zb;
            float m = wave_sum_u(zb) * 0.015625f;
            if (lane == 0) mub[t] = m;
        }
    };

    stage_async(0, 0);
    asm volatile("s_waitcnt vmcnt(0)" ::: "memory");
    __builtin_amdgcn_sched_barrier(0);
    matvec16(0, 0);

    bf16* xq = xqw + ((size_t)b * L_SEQ) * DM + h * 64 + lane;

    for (int c = 0; c < NSB; ++c) {
        const int cur = c & 1;
        if (c + 1 < NSB) stage_async(c + 1, 1 - cur);
#pragma unroll 1
        for (int sub = 0; sub < 4; ++sub) {
            const int t0 = sub * CHT;
            float eg[CHT];
            float bacc = 0.f;
            float4 krA, krB, krC, krD;
            {
                const float4* krow = (const float4*)&kb[cur][sub][0][0];
                krA = krow[0]; krB = krow[1]; krC = krow[2]; krD = krow[3];
            }
            float zb_n = zbb[0][lane];
            float xk_n = xkb[cur][t0 + 0][lane];
            float xv_n = b2f(xvb[cur][t0 + 0][lane]);
            float et_n = sc[cur][0][t0 + 0];
            float q0_n = sc[cur][1][t0 + 0];
            float mu_n = mub[0];
#pragma unroll
            for (int t = 0; t < CHT; ++t) {
                float kr[CHT];
                *(float4*)&kr[0]  = krA;
                *(float4*)&kr[4]  = krB;
                *(float4*)&kr[8]  = krC;
                *(float4*)&kr[12] = krD;
                float zb_v = zb_n;
                float xk_c = xk_n;
                float xv_c = xv_n;
                float eta  = et_n;
                float q0u  = q0_n;
                float muv  = mu_n;
                if (t + 1 < CHT) {
                    const float4* krow = (const float4*)&kb[cur][sub][t + 1][0];
                    krA = krow[0]; krB = krow[1]; krC = krow[2]; krD = krow[3];
                    zb_n = zbb[t + 1][lane];
                    xk_n = xkb[cur][t0 + t + 1][lane];
                    xv_n = b2f(xvb[cur][t0 + t + 1][lane]);
                    et_n = sc[cur][0][t0 + t + 1];
                    q0_n = sc[cur][1][t0 + t + 1];
                    mu_n = mub[t + 1];
                }

                float gg0 = bacc, gg1 = 0.f, gg2 = 0.f, gg3 = 0.f;
#pragma unroll
                for (int s = 0; s < t; ++s) {
                    if ((s & 3) == 0) gg0 = fmaf(kr[s], eg[s], gg0);
                    else if ((s & 3) == 1) gg1 = fmaf(kr[s], eg[s], gg1);
                    else if ((s & 3) == 2) gg2 = fmaf(kr[s], eg[s], gg2);
                    else gg3 = fmaf(kr[s], eg[s], gg3);
                }
                float z1 = zb_v - ((gg0 + gg1) + (gg2 + gg3));
                float d = z1 - muv;
                float q = (lb - xv_c + xk_c) * lw;
                float S2  = wave_sum_u(d * d);
                float PZ1 = wave_sum_u(p * d);
                float PZ2 = wave_sum_u(p * d * d);
                float Q1  = wave_sum_u(q * d);
                float istd = rsqrtf(S2 * 0.015625f + 1e-6f);
                float A_ = fmaf(istd, PZ1, q0u);
                float Bv = fmaf(istd * istd, PZ2, istd * Q1);
                float xh = d * istd;
                float gxh = fmaf(p, xh, q);
                float grad = (64.f * gxh - A_ - xh * Bv) * (istd * 0.015625f);
                float egt = eta * grad;
                eg[t] = egt;
                egb[t][lane] = egt;
                z1qb[t][lane] = fmaf(-eta * (kr[t] + 1.f), grad, z1);
                bacc += egt;
            }
#pragma unroll 4
            for (int t = 0; t < CHT; ++t) {
                float dq = z1qb[t][lane] - mub[t];
                float SQ = wave_sum_u(dq * dq);
                float istd2 = rsqrtf(SQ * 0.015625f + 1e-6f);
                float xk_c = xkb[cur][t0 + t][lane];
                float outv = fmaf(lw, dq * istd2, xk_c + lb);
                xq[(size_t)(c * SB + t0 + t) * DM] = f2b(outv);
            }
            bool last = (c == NSB - 1) && (sub == 3);
            if (!last) {
#pragma unroll 2
                for (int s = 0; s < CHT; ++s) {
                    float egs = egb[s][lane];
                    const float4* row = (const float4*)&xkb[cur][t0 + s][0];
#pragma unroll
                    for (int j = 0; j < 16; ++j) {
                        float4 kv = row[j];
                        W[4 * j + 0] = fmaf(-egs, kv.x, W[4 * j + 0]);
                        W[4 * j + 1] = fmaf(-egs, kv.y, W[4 * j + 1]);
                        W[4 * j + 2] = fmaf(-egs, kv.z, W[4 * j + 2]);
                        W[4 * j + 3] = fmaf(-egs, kv.w, W[4 * j + 3]);
                    }
                }
                bvec -= bacc;
                int nbuf = cur, nt0 = t0 + CHT;
                if (sub == 3) {
                    nbuf = 1 - cur; nt0 = 0;
                    asm volatile("s_waitcnt vmcnt(0)" ::: "memory");
                    __builtin_amdgcn_sched_barrier(0);
                }
                matvec16(nbuf, nt0);
            }
        }
    }
}

// ---------------------------------------------------------------- hetero: blocks 0-31 ttt, blocks 32+ fused zlg GEMM (N=1536)
__global__ __launch_bounds__(256) void hetero_k(const bf16* __restrict__ proj,
                                                const float* __restrict__ xkf,
                                                const float* __restrict__ etav,
                                                const float* __restrict__ q0s,
                                                const float* __restrict__ gram16,
                                                const float* __restrict__ W1,
                                                const float* __restrict__ b1,
                                                const float* __restrict__ ln_w,
                                                const float* __restrict__ ln_b,
                                                bf16* __restrict__ xqw,
                                                const bf16* __restrict__ hred,
                                                const bf16* __restrict__ wcat,
                                                bf16* __restrict__ zl,
                                                bf16* __restrict__ gq,
                                                bf16* __restrict__ gk) {
    if (blockIdx.x < 32) {
        if (threadIdx.x < 64)
            ttt_body(proj, xkf, etav, q0s, gram16, W1, b1, ln_w, ln_b, xqw);
        return;
    }
    __shared__ __align__(16) bf16 As[128 * 48];
    __shared__ __align__(16) bf16 Ws[128 * 48];
    const int bidx = blockIdx.x - 32;
    const int tid = threadIdx.x;
    const int lane = tid & 63;
    const int widx = tid >> 6;
    const int bm = (bidx & 63) * 128;
    const int bn = (bidx >> 6) * 128;
    const int wr = (widx >> 1) * 64;
    const int wc = (widx & 1) * 64;

    f32x4 acc[4][4];
#pragma unroll
    for (int i = 0; i < 4; ++i)
#pragma unroll
        for (int j = 0; j < 4; ++j) acc[i][j] = (f32x4){0.f, 0.f, 0.f, 0.f};

    const int r0 = tid >> 2;
    const int c0 = tid & 3;
    const int frow = lane & 15;
    const int fk = (lane >> 4) * 8;

    const bf16* pa0 = hred + (size_t)(bm + r0) * DM + c0 * 8;
    const bf16* pa1 = hred + (size_t)(bm + r0 + 64) * DM + c0 * 8;
    const bf16* pb0 = wcat + (size_t)(bn + r0) * DM + c0 * 8;
    const bf16* pb1 = wcat + (size_t)(bn + r0 + 64) * DM + c0 * 8;

    for (int k0 = 0; k0 < DM; k0 += 32) {
        short8v a0 = *(const short8v*)(pa0 + k0);
        short8v a1 = *(const short8v*)(pa1 + k0);
        short8v b0 = *(const short8v*)(pb0 + k0);
        short8v b1 = *(const short8v*)(pb1 + k0);
        __syncthreads();
        *(short8v*)&As[r0 * 48 + c0 * 8] = a0;
        *(short8v*)&As[(r0 + 64) * 48 + c0 * 8] = a1;
        *(short8v*)&Ws[r0 * 48 + c0 * 8] = b0;
        *(short8v*)&Ws[(r0 + 64) * 48 + c0 * 8] = b1;
        __syncthreads();
        short8v af[4], bg[4];
#pragma unroll
        for (int mi = 0; mi < 4; ++mi)
            af[mi] = *(const short8v*)&As[(wr + mi * 16 + frow) * 48 + fk];
#pragma unroll
        for (int ni = 0; ni < 4; ++ni)
            bg[ni] = *(const short8v*)&Ws[(wc + ni * 16 + frow) * 48 + fk];
#pragma unroll
        for (int mi = 0; mi < 4; ++mi)
#pragma unroll
            for (int ni = 0; ni < 4; ++ni)
                acc[mi][ni] = __builtin_amdgcn_mfma_f32_16x16x32_bf16(
                    af[mi], bg[ni], acc[mi][ni], 0, 0, 0);
    }

#pragma unroll
    for (int ni = 0; ni < 4; ++ni) {
        int col = bn + wc + ni * 16 + (lane & 15);
        int buf = col >> 9;
        int lc = col & 511;
        bf16* Cb = (buf == 0) ? zl : (buf == 1) ? gq : gk;
#pragma unroll
        for (int mi = 0; mi < 4; ++mi) {
            int rbase = bm + wr + mi * 16 + (lane >> 4) * 4;
#pragma unroll
            for (int r = 0; r < 4; ++r)
                Cb[(size_t)(rbase + r) * 512 + lc] = f2b(acc[mi][ni][r]);
        }
    }
}

// ---------------------------------------------------------------- post-norm + gelu gate
__global__ __launch_bounds__(256) void gated_k(const bf16* __restrict__ xqw,
                                               const bf16* __restrict__ proj,
                                               const float* __restrict__ pnw,
                                               const float* __restrict__ pnb,
                                               bf16* __restrict__ gated) {
    int r = blockIdx.x, tid = threadIdx.x;
    const bf16* row = xqw + (size_t)r * DM;
    float v0 = b2f(row[tid]), v1 = b2f(row[tid + 256]);
    float s = v0 + v1, q = v0 * v0 + v1 * v1;
#pragma unroll
    for (int off = 32; off; off >>= 1) {
        s += __shfl_xor(s, off);
        q += __shfl_xor(q, off);
    }
    __shared__ float sm[8];
    if ((tid & 63) == 0) { sm[tid >> 6] = s; sm[4 + (tid >> 6)] = q; }
    __syncthreads();
    s = sm[0] + sm[1] + sm[2] + sm[3];
    q = sm[4] + sm[5] + sm[6] + sm[7];
    float mu = s * (1.f / 512.f);
    float var = q * (1.f / 512.f) - mu * mu;
    float istd = rsqrtf(var + 1e-5f);
    const bf16* grow = proj + (size_t)r * PROJW + 1024;
    bf16* orow = gated + (size_t)r * DM;
#pragma unroll
    for (int e = 0; e < 2; ++e) {
        int c = tid + e * 256;
        float xv = (e == 0) ? v0 : v1;
        float nv = (xv - mu) * istd * pnw[c] + pnb[c];
        float g = b2f(grow[c]);
        float gg = 0.5f * g * (1.f + tanhf(0.7978845608028654f * (g + 0.044715f * g * g * g)));
        orow[c] = f2b(gg * nv);
    }
}

// ---------------------------------------------------------------- gq mean (bf16 input), two-phase
__global__ __launch_bounds__(256) void mean1_k(const bf16* __restrict__ gq,
                                               float* __restrict__ partial) {
    int blk = blockIdx.x;
    int b = blk >> 4, c = blk & 15;
    int tid = threadIdx.x;
    const bf16* p = gq + ((size_t)b * L_SEQ + c * 128) * DM + tid * 2;
    float a0 = 0.f, a1 = 0.f;
    for (int l = 0; l < 128; ++l) {
        ushort2 u = *(const ushort2*)(p + (size_t)l * DM);
        a0 += us2f(u.x); a1 += us2f(u.y);
    }
    partial[(size_t)blk * DM + tid * 2]     = a0;
    partial[(size_t)blk * DM + tid * 2 + 1] = a1;
}
__global__ __launch_bounds__(256) void mean2_k(const float* __restrict__ partial,
                                               float* __restrict__ gqm) {
    int t = blockIdx.x * 256 + threadIdx.x;
    if (t >= 2048) return;
    int b = t >> 9, d = t & 511;
    float acc = 0.f;
#pragma unroll
    for (int c = 0; c < 16; ++c) acc += partial[(size_t)(b * 16 + c) * DM + d];
    gqm[t] = acc * (1.f / 2048.f);
}

// ---------------------------------------------------------------- gain + final mix (bf16 z inputs)
__global__ __launch_bounds__(64) void final_k(const bf16* __restrict__ zl,
                                              const bf16* __restrict__ zt,
                                              const bf16* __restrict__ gk,
                                              const float* __restrict__ gqm,
                                              const float* __restrict__ alpha,
                                              const float* __restrict__ beta,
                                              float* __restrict__ out,
                                              float* __restrict__ gain_out) {
    int r = blockIdx.x;
    int lane = threadIdx.x;
    int b = r >> 11;
    const bf16* gkr = gk + (size_t)r * DM;
    const float* gmb = gqm + b * DM;
    float acc = 0.f;
#pragma unroll
    for (int i = 0; i < 8; ++i) acc = fmaf(gmb[lane + 64 * i], b2f(gkr[lane + 64 * i]), acc);
#pragma unroll
    for (int off = 32; off; off >>= 1) acc += __shfl_xor(acc, off);
    float score = acc * 0.04419417382415922f;
    float g = sigmoidf_(alpha[0] * score + beta[0]);
    g = fminf(g, 0.55f);
    if (lane == 0) gain_out[r] = g;
    const bf16* zlr = zl + (size_t)r * DM;
    const bf16* ztr = zt + (size_t)r * DM;
    float* orow = out + (size_t)r * DM;
#pragma unroll
    for (int i = 0; i < 8; ++i) {
        int c = lane + 64 * i;
        float a = b2f(zlr[c]);
        orow[c] = a + g * (b2f(ztr[c]) - a);
    }
}

// ---------------------------------------------------------------- host launcher

extern "C" void kernel_launch(void* const* d_in, const int* in_sizes, int n_in,
                              void* d_out, int out_size, void* d_ws, size_t ws_size,
                              hipStream_t stream) {
    const float* x           = (const float*)d_in[0];
    const float* norm_w      = (const float*)d_in[1];
    const float* in_proj_w   = (const float*)d_in[2];
    const float* conv_w      = (const float*)d_in[3];
    const float* conv_b      = (const float*)d_in[4];
    const float* x_proj_w    = (const float*)d_in[5];
    const float* dt_head_w   = (const float*)d_in[6];
    const float* dt_head_b   = (const float*)d_in[7];
    const float* Dvec        = (const float*)d_in[8];
    const float* reduce_w    = (const float*)d_in[9];
    const float* q_net_w     = (const float*)d_in[10];
    const float* gain_q_w    = (const float*)d_in[11];
    const float* gain_k_w    = (const float*)d_in[12];
    const float* alpha       = (const float*)d_in[13];
    const float* beta        = (const float*)d_in[14];
    const float* qkv_w       = (const float*)d_in[15];
    const float* qkv_b       = (const float*)d_in[16];
    const float* ttt_lr_bias = (const float*)d_in[17];
    const float* W1          = (const float*)d_in[18];
    const float* b1          = (const float*)d_in[19];
    const float* token_idx   = (const float*)d_in[20];
    const float* token_bias  = (const float*)d_in[21];
    const float* ttt_ln_w    = (const float*)d_in[22];
    const float* ttt_ln_b    = (const float*)d_in[23];
    const float* post_norm_w = (const float*)d_in[24];
    const float* post_norm_b = (const float*)d_in[25];
    const float* wo_w        = (const float*)d_in[26];
    const float* wo_b        = (const float*)d_in[27];

    const size_t SZ_ROWDM = (size_t)NROWS * DM;
    const size_t MB = 1024u * 1024u;
    const size_t KB = 1024u;
    char* base = (char*)d_ws;

    float* out_p  = (float*)d_out;
    float* res_p  = out_p + SZ_ROWDM;
    float* gain_p = out_p + 2 * SZ_ROWDM;

    if (ws_size < 116 * MB) {
        copy4_k<<<(int)(SZ_ROWDM / 4 / 256), 256, 0, stream>>>(
            (const float4*)x, (float4*)res_p, (int)(SZ_ROWDM / 4));
        return;
    }

    // ---- workspace layout; lifetimes (step = launch order below):
    //  [0,6)       in_proj bf16 (w@2a, r@2b) -> lpq part
    //  [6,6.6)     xpb (w@5a, r@5b) -> lpq part
    //  [0,12.58)   lpq (w@6a, rw@6b, r@6c)  [in_proj bf16 + xpb dead by then]
    //              -> redb [0,3) (w@7, r@8) -> qkvb [3,4.51) (w@7, r@9)
    //              -> wob16 [4.75,5.25) (w@7, r@13)
    //  [7,15)      xn (w@1, r@2) -> cside (w@4a, r@4b) -> h_red (w@8, r@9,11)
    //  [16,64)     bufX: xx/xb/y (w@2, rw@4,5,6, r@8) -> proj (w@9, r@10,11,12)
    //  [42,58)     xkf (w@10, r@11) -> chid [42,50) (w@13a, r@13b)
    //  [58,58.25)  etav ; [58.5,58.75) q0s (w@10, r@11)
    //  [64,112)    bufZ: z (w@2, r@6) -> xqw [64,72) (w@11, r@12)
    //              zl [72,80) ; gq [80,88) (w@11, r@14) ; gramb [88,92) (w@10, r@11)
    //              gk [92,100) (w@11, r@14) ; zttt [100,104) (w@13, r@14)
    //              gated [104,112) (w@12, r@13)
    //  [112,113.5) xdbl (w@5, r@6)
    //  [113.5,113.6) gqm ; [114,114.125) mpart (w@14)
    //  [114.5,116) wcat (w@3, r@11,13)
    bf16*  inpb   = (bf16*)base;                    // in_proj bf16 [0,6)
    bf16*  xpb    = (bf16*)(base + 6 * MB);         // [6,6.6)
    float* lpq    = (float*)base;                   // [0,12.58)
    bf16*  redb   = (bf16*)base;                    // [0,3)
    bf16*  qkvb   = (bf16*)(base + 3 * MB);         // [3,4.51)
    bf16*  wob16  = (bf16*)(base + 4 * MB + 768 * KB);
    bf16*  wcat   = (bf16*)(base + 114 * MB + 512 * KB);
    bf16*  xn     = (bf16*)(base + 7 * MB);
    bf16*  h_red  = xn;
    bf16*  cside  = (bf16*)(base + 7 * MB);
    bf16*  bufX   = (bf16*)(base + 16 * MB);
    bf16*  bufZ   = (bf16*)(base + 64 * MB);
    float* xdbl   = (float*)(base + 112 * MB);
    float* gqm    = (float*)(base + 113 * MB + 512 * KB);
    float* mpart  = (float*)(base + 114 * MB);
    bf16*  proj   = bufX;
    bf16*  xqw    = bufZ;
    bf16*  zl     = (bf16*)(base + 72 * MB);
    bf16*  gq     = (bf16*)(base + 80 * MB);
    float* gramb  = (float*)(base + 88 * MB);
    bf16*  gk     = (bf16*)(base + 92 * MB);
    bf16*  zttt   = (bf16*)(base + 100 * MB);
    bf16*  gated  = (bf16*)(base + 104 * MB);
    bf16*  chid   = (bf16*)(base + 42 * MB);
    float* xkf    = (float*)(base + 42 * MB);
    float* etav   = (float*)(base + 58 * MB);
    float* q0s    = (float*)(base + 58 * MB + 512 * KB);

    // 1. rmsnorm + residual
    rmsnorm_res_k<<<NROWS, 256, 0, stream>>>(x, norm_w, xn, res_p);

    // 2. in_proj cvt + merged GEMM (N=6144 -> bufX|bufZ)
    cvt_k<<<(2 * DI * DM / 4 + 255) / 256, 256, 0, stream>>>(in_proj_w, inpb, 2 * DI * DM / 4);
    {
        dim3 g(NROWS / 128, 2 * DI / 128);
        gemm_inproj<<<g, 256, 0, stream>>>(xn, inpb, bufX, bufZ);
    }

    // 3. wcat cvt (isolated region, needed at step 11)
    cvt3_k<<<(3 * 65536 + 255) / 256, 256, 0, stream>>>(q_net_w, gain_q_w, gain_k_w, wcat);

    // 4. conv
    conv_boundary_k<<<((L_SEQ / CTILE - 1) * 2 * BDI) / 256, 256, 0, stream>>>(bufX, cside);
    conv_tile_k<<<((L_SEQ / CTILE) * BDI) / 256, 256, 0, stream>>>(bufX, cside, conv_w, conv_b);

    // 5. x_proj cvt + gemm
    cvt_k<<<(48 * DI / 4 + 255) / 256, 256, 0, stream>>>(x_proj_w, xpb, 48 * DI / 4);
    {
        dim3 g(NROWS / 128, 1);
        gemm_mfma<0, float><<<g, 256, 0, stream>>>(bufX, DI, xpb, DI, nullptr, xdbl, 48, 48, DI);
    }

    // 6. longhorn chunked scan (lpq over dead in_proj/xpb scratch)
    longhorn_p1<<<(NLCH * BDI) / 256, 256, 0, stream>>>(bufX, xdbl, dt_head_w, dt_head_b, lpq);
    longhorn_p2<<<BDI / 256, 256, 0, stream>>>(lpq);
    longhorn_p3<<<(NLCH * BDI) / 256, 256, 0, stream>>>(bufX, bufZ, xdbl, dt_head_w,
                                                        dt_head_b, Dvec, lpq);

    // 7. reduce/qkv/wo cvt (over dead lpq)
    cvt_rqw_k<<<(C_RED + C_QKV + C_WO + 255) / 256, 256, 0, stream>>>(
        reduce_w, qkv_w, wo_w, redb, qkvb, wob16);

    // 8. reduce -> h_red
    {
        dim3 g(NROWS / 128, DM / 128);
        gemm_mfma<0, bf16><<<g, 256, 0, stream>>>(bufX, DI, redb, DI, nullptr, h_red, DM, DM, DI);
    }

    // 9. qkv -> proj
    {
        dim3 g(NROWS / 128, (PROJW + 127) / 128);
        gemm_mfma<1, bf16><<<g, 256, 0, stream>>>(h_red, DM, qkvb, DM, qkv_b, proj, PROJW, PROJW, DM);
    }

    // 10. fused prep+gram
    prep_gram_k<<<32 * 16, 128, 0, stream>>>(proj, ttt_lr_bias, token_idx, token_bias,
                                             ttt_ln_w, ttt_ln_b, xkf, etav, q0s, gramb);

    // 11. hetero: ttt + zl/gq/gk GEMM overlapped
    hetero_k<<<32 + 768, 256, 0, stream>>>(proj, xkf, etav, q0s, gramb, W1, b1,
                                           ttt_ln_w, ttt_ln_b, xqw,
                                           h_red, wcat, zl, gq, gk);

    // 12. gated
    gated_k<<<NROWS, 256, 0, stream>>>(xqw, proj, post_norm_w, post_norm_b, gated);

    // 13. wo -> chid ; zttt = chid @ q_net (wcat rows 0-511)
    {
        dim3 g(NROWS / 128, DM / 128);
        gemm_mfma<1, bf16><<<g, 256, 0, stream>>>(gated, DM, wob16, DM, wo_b, chid, DM, DM, DM);
        gemm_mfma<0, bf16><<<g, 256, 0, stream>>>(chid, DM, wcat, DM, nullptr, zttt, DM, DM, DM);
    }

    // 14. gq mean + final
    mean1_k<<<64, 256, 0, stream>>>(gq, mpart);
    mean2_k<<<8, 256, 0, stream>>>(mpart, gqm);
    final_k<<<NROWS, 64, 0, stream>>>(zl, zttt, gk, gqm, alpha, beta, out_p, gain_p);
}